// Round 7
// baseline (7905.719 us; speedup 1.0000x reference)
//
#include <hip/hip_runtime.h>
#include <hip/hip_bf16.h>

#define NNODE 8192
#define DEG   32
#define DIN   256
#define EDIM  64
#define KC    576            // 2*DIN + EDIM
#define DD    512            // internal width D
#define MEDGE (NNODE*DEG)
#define XDP   264            // 256 + 8 bf16 pad (full x[dst] tile pitch)

typedef __attribute__((ext_vector_type(8))) short short8;
typedef __attribute__((ext_vector_type(4))) short short4v;
typedef __attribute__((ext_vector_type(4))) float floatx4;
typedef __attribute__((ext_vector_type(4))) unsigned int uint4v;
typedef unsigned int u32;

__device__ __forceinline__ ushort f2bf(float f) {
  union { float f; unsigned int i; } v; v.f = f;
  return (ushort)((v.i + 0x7fffu + ((v.i >> 16) & 1u)) >> 16);
}
__device__ __forceinline__ u32 pk2(float a, float b) {
  return (u32)f2bf(a) | ((u32)f2bf(b) << 16);
}
__device__ __forceinline__ float gelu_f(float z) {
  return 0.5f * z * (1.0f + erff(z * 0.70710678118654752f));
}
__device__ __forceinline__ floatx4 zero4() { floatx4 v = {0.f, 0.f, 0.f, 0.f}; return v; }

__device__ __forceinline__ short8 ld_cvt8(const float* __restrict__ p) {
  floatx4 a = *(const floatx4*)(p);
  floatx4 b = *(const floatx4*)(p + 4);
  short8 r;
  r[0] = (short)f2bf(a[0]); r[1] = (short)f2bf(a[1]);
  r[2] = (short)f2bf(a[2]); r[3] = (short)f2bf(a[3]);
  r[4] = (short)f2bf(b[0]); r[5] = (short)f2bf(b[1]);
  r[6] = (short)f2bf(b[2]); r[7] = (short)f2bf(b[3]);
  return r;
}

#define MFMA16(a, b, c) __builtin_amdgcn_mfma_f32_16x16x32_bf16((a), (b), (c), 0, 0, 0)

// D-layout -> A/B-frag-layout in-register transform (verified r2-r6).
__device__ __forceinline__ u32 bpsel(int a, u32 v0, u32 v1, bool hi) {
  u32 x0 = (u32)__builtin_amdgcn_ds_bpermute(a, (int)v0);
  u32 x1 = (u32)__builtin_amdgcn_ds_bpermute(a, (int)v1);
  return hi ? x1 : x0;
}
__device__ __forceinline__ short8 frag4(int a0, int a1, bool hi,
                                        u32 t00, u32 t01, u32 t10, u32 t11) {
  uint4v r;
  r[0] = bpsel(a0, t00, t10, hi);
  r[1] = bpsel(a0, t01, t11, hi);
  r[2] = bpsel(a1, t00, t10, hi);
  r[3] = bpsel(a1, t01, t11, hi);
  union { uint4v u; short8 s; } c; c.u = r; return c.s;
}

// ============================================================================
// K1: ex = gelu(gelu(feat @ Wc^T + bc))  -> exC (bf16 row-major [64*grid][512])
// block: 256 thr / 4 waves, 2 nodes (64 edges). LDS: full x[dst] tile.
// ============================================================================
__global__ __launch_bounds__(256, 3) void k1_ex(
    const float* __restrict__ x,  const float* __restrict__ ea,
    const int*   __restrict__ e,
    const ushort* __restrict__ Wc, const float* __restrict__ bc,
    ushort* __restrict__ exC, int n0)
{
  __shared__ __align__(16) ushort sXD[64 * XDP];   // x[dst] [64][256] bf16

  const int m0   = (n0 + blockIdx.x * 2) * DEG;
  const int lex0 = blockIdx.x * 64;
  const int tid  = threadIdx.x;
  const int w    = tid >> 6;
  const int l    = tid & 63;
  const int lr   = l & 15;
  const int lg   = l >> 4;

  // stage full x[dst] tile: 4 threads/row, 64 cols each
  {
    const int srow = tid >> 2;
    const int sc0  = (tid & 3) * 64;
    const float* sxp = x + (size_t)e[MEDGE + m0 + srow] * DIN + sc0;
    #pragma unroll
    for (int j = 0; j < 4; ++j) {
      floatx4 f0 = *(const floatx4*)(sxp + j * 16);
      floatx4 f1 = *(const floatx4*)(sxp + j * 16 + 4);
      floatx4 f2 = *(const floatx4*)(sxp + j * 16 + 8);
      floatx4 f3 = *(const floatx4*)(sxp + j * 16 + 12);
      short8 p0, p1;
      #pragma unroll
      for (int q = 0; q < 4; ++q) {
        p0[q] = (short)f2bf(f0[q]); p0[4 + q] = (short)f2bf(f1[q]);
        p1[q] = (short)f2bf(f2[q]); p1[4 + q] = (short)f2bf(f3[q]);
      }
      *(short8*)(&sXD[srow * XDP + sc0 + j * 16])     = p0;
      *(short8*)(&sXD[srow * XDP + sc0 + j * 16 + 8]) = p1;
    }
  }
  const float* xsrc0 = x + (size_t)e[m0] * DIN;
  const float* xsrc1 = x + (size_t)e[m0 + DEG] * DIN;
  __syncthreads();

  for (int p = 0; p < 2; ++p) {
    const int cb = w * 128 + p * 64;
    floatx4 acc[4][4];
    #pragma unroll
    for (int mt = 0; mt < 4; ++mt)
      #pragma unroll
      for (int nt = 0; nt < 4; ++nt) acc[mt][nt] = zero4();

    // k 0..255 : x[src]
    for (int s = 0; s < 8; ++s) {
      short8 bfr[4];
      #pragma unroll
      for (int nt = 0; nt < 4; ++nt)
        bfr[nt] = *(const short8*)(Wc + (size_t)(cb + nt * 16 + lr) * KC + s * 32 + lg * 8);
      short8 a0 = ld_cvt8(xsrc0 + s * 32 + lg * 8);
      short8 a1 = ld_cvt8(xsrc1 + s * 32 + lg * 8);
      #pragma unroll
      for (int nt = 0; nt < 4; ++nt) {
        acc[0][nt] = MFMA16(a0, bfr[nt], acc[0][nt]);
        acc[2][nt] = MFMA16(a1, bfr[nt], acc[2][nt]);
      }
    }
    #pragma unroll
    for (int nt = 0; nt < 4; ++nt) { acc[1][nt] = acc[0][nt]; acc[3][nt] = acc[2][nt]; }

    // k 256..511 : x[dst] from sXD
    for (int s = 0; s < 8; ++s) {
      short8 bfr[4];
      #pragma unroll
      for (int nt = 0; nt < 4; ++nt)
        bfr[nt] = *(const short8*)(Wc + (size_t)(cb + nt * 16 + lr) * KC + 256 + s * 32 + lg * 8);
      #pragma unroll
      for (int mt = 0; mt < 4; ++mt) {
        short8 af = *(const short8*)(&sXD[(mt * 16 + lr) * XDP + s * 32 + lg * 8]);
        #pragma unroll
        for (int nt = 0; nt < 4; ++nt)
          acc[mt][nt] = MFMA16(af, bfr[nt], acc[mt][nt]);
      }
    }

    // k 512..575 : edge_attr
    for (int s = 0; s < 2; ++s) {
      short8 bfr[4];
      #pragma unroll
      for (int nt = 0; nt < 4; ++nt)
        bfr[nt] = *(const short8*)(Wc + (size_t)(cb + nt * 16 + lr) * KC + 512 + s * 32 + lg * 8);
      #pragma unroll
      for (int mt = 0; mt < 4; ++mt) {
        short8 af = ld_cvt8(ea + (size_t)(m0 + mt * 16 + lr) * EDIM + s * 32 + lg * 8);
        #pragma unroll
        for (int nt = 0; nt < 4; ++nt)
          acc[mt][nt] = MFMA16(af, bfr[nt], acc[mt][nt]);
      }
    }

    // epilogue -> exC
    #pragma unroll
    for (int nt = 0; nt < 4; ++nt) {
      const int col = cb + nt * 16 + lr;
      const float bias = bc[col];
      #pragma unroll
      for (int mt = 0; mt < 4; ++mt)
        #pragma unroll
        for (int i = 0; i < 4; ++i)
          exC[(size_t)(lex0 + mt * 16 + lg * 4 + i) * DD + col] =
              f2bf(gelu_f(gelu_f(acc[mt][nt][i] + bias)));
    }
  }
}

// ============================================================================
// K2: per-head attention. 512 thr / 8 waves, wave = head; 2 nodes (64 edges).
// Zero LDS, zero barriers. ex from global; AO to global.
// ============================================================================
__global__ __launch_bounds__(512, 3) void k2_attn(
    const ushort* __restrict__ exC,
    const ushort* __restrict__ Wi, const float* __restrict__ bi,
    ushort* __restrict__ aoC, int n0)
{
  const int lex0 = blockIdx.x * 64;
  const int tid  = threadIdx.x;
  const int w    = tid >> 6;    // head 0..7
  const int l    = tid & 63;
  const int lr   = l & 15;
  const int lg   = l >> 4;
  (void)n0;

  const int qb = w * 64, kb = 512 + w * 64, vb = 1024 + w * 64;
  const int pa0 = ((2 * (lg & 1)) * 16 + lr) * 4;
  const int pa1 = pa0 + 64;
  const bool hi = ((lg >> 1) & 1) != 0;

  // ---- Q' transposed pass (rows=qkcol, cols=edges), et-split halves
  u32 qpk[4][4][2];
  #pragma unroll
  for (int eh = 0; eh < 2; ++eh) {
    floatx4 qacc[4][2];
    #pragma unroll
    for (int mt = 0; mt < 4; ++mt)
      #pragma unroll
      for (int e2 = 0; e2 < 2; ++e2) qacc[mt][e2] = zero4();
    for (int ks = 0; ks < 16; ++ks) {
      short8 wq[4];
      #pragma unroll
      for (int mt = 0; mt < 4; ++mt)
        wq[mt] = *(const short8*)(Wi + (size_t)(qb + mt * 16 + lr) * DD + ks * 32 + lg * 8);
      #pragma unroll
      for (int e2 = 0; e2 < 2; ++e2) {
        short8 exf = *(const short8*)(exC + (size_t)(lex0 + (2 * eh + e2) * 16 + lr) * DD + ks * 32 + lg * 8);
        #pragma unroll
        for (int mt = 0; mt < 4; ++mt)
          qacc[mt][e2] = MFMA16(wq[mt], exf, qacc[mt][e2]);
      }
    }
    #pragma unroll
    for (int mt = 0; mt < 4; ++mt) {
      float b0 = bi[qb + mt * 16 + lg * 4 + 0];
      float b1 = bi[qb + mt * 16 + lg * 4 + 1];
      float b2 = bi[qb + mt * 16 + lg * 4 + 2];
      float b3 = bi[qb + mt * 16 + lg * 4 + 3];
      #pragma unroll
      for (int e2 = 0; e2 < 2; ++e2) {
        qpk[mt][2 * eh + e2][0] = pk2(qacc[mt][e2][0] + b0, qacc[mt][e2][1] + b1);
        qpk[mt][2 * eh + e2][1] = pk2(qacc[mt][e2][2] + b2, qacc[mt][e2][3] + b3);
      }
    }
  }

  // ---- K' transposed pass, et-split halves
  u32 kpk[4][4][2];
  #pragma unroll
  for (int eh = 0; eh < 2; ++eh) {
    floatx4 kacc[4][2];
    #pragma unroll
    for (int mt = 0; mt < 4; ++mt)
      #pragma unroll
      for (int e2 = 0; e2 < 2; ++e2) kacc[mt][e2] = zero4();
    for (int ks = 0; ks < 16; ++ks) {
      short8 wk[4];
      #pragma unroll
      for (int mt = 0; mt < 4; ++mt)
        wk[mt] = *(const short8*)(Wi + (size_t)(kb + mt * 16 + lr) * DD + ks * 32 + lg * 8);
      #pragma unroll
      for (int e2 = 0; e2 < 2; ++e2) {
        short8 exf = *(const short8*)(exC + (size_t)(lex0 + (2 * eh + e2) * 16 + lr) * DD + ks * 32 + lg * 8);
        #pragma unroll
        for (int mt = 0; mt < 4; ++mt)
          kacc[mt][e2] = MFMA16(wk[mt], exf, kacc[mt][e2]);
      }
    }
    #pragma unroll
    for (int mt = 0; mt < 4; ++mt) {
      float b0 = bi[kb + mt * 16 + lg * 4 + 0];
      float b1 = bi[kb + mt * 16 + lg * 4 + 1];
      float b2 = bi[kb + mt * 16 + lg * 4 + 2];
      float b3 = bi[kb + mt * 16 + lg * 4 + 3];
      #pragma unroll
      for (int e2 = 0; e2 < 2; ++e2) {
        kpk[mt][2 * eh + e2][0] = pk2(kacc[mt][e2][0] + b0, kacc[mt][e2][1] + b1);
        kpk[mt][2 * eh + e2][1] = pk2(kacc[mt][e2][2] + b2, kacc[mt][e2][3] + b3);
      }
    }
  }

  // ---- scores + softmax per node
  u32 ppk[2][2][4];   // [node][ke-tile][2*qt+p]
  #pragma unroll
  for (int n = 0; n < 2; ++n) {
    floatx4 sacc[2][2];
    #pragma unroll
    for (int a = 0; a < 2; ++a)
      #pragma unroll
      for (int b = 0; b < 2; ++b) sacc[a][b] = zero4();
    #pragma unroll
    for (int kt = 0; kt < 2; ++kt) {
      short8 afr0 = frag4(pa0, pa1, hi, kpk[2*kt][2*n][0],   kpk[2*kt][2*n][1],   kpk[2*kt+1][2*n][0],   kpk[2*kt+1][2*n][1]);
      short8 afr1 = frag4(pa0, pa1, hi, kpk[2*kt][2*n+1][0], kpk[2*kt][2*n+1][1], kpk[2*kt+1][2*n+1][0], kpk[2*kt+1][2*n+1][1]);
      short8 bfr0 = frag4(pa0, pa1, hi, qpk[2*kt][2*n][0],   qpk[2*kt][2*n][1],   qpk[2*kt+1][2*n][0],   qpk[2*kt+1][2*n][1]);
      short8 bfr1 = frag4(pa0, pa1, hi, qpk[2*kt][2*n+1][0], qpk[2*kt][2*n+1][1], qpk[2*kt+1][2*n+1][0], qpk[2*kt+1][2*n+1][1]);
      sacc[0][0] = MFMA16(afr0, bfr0, sacc[0][0]);
      sacc[0][1] = MFMA16(afr0, bfr1, sacc[0][1]);
      sacc[1][0] = MFMA16(afr1, bfr0, sacc[1][0]);
      sacc[1][1] = MFMA16(afr1, bfr1, sacc[1][1]);
    }
    #pragma unroll
    for (int nt = 0; nt < 2; ++nt) {
      float s[2][4];
      float mx = -1e30f;
      #pragma unroll
      for (int mt = 0; mt < 2; ++mt)
        #pragma unroll
        for (int i = 0; i < 4; ++i) {
          s[mt][i] = sacc[mt][nt][i] * 0.125f;
          mx = fmaxf(mx, s[mt][i]);
        }
      mx = fmaxf(mx, __shfl_xor(mx, 16));
      mx = fmaxf(mx, __shfl_xor(mx, 32));
      float sm = 0.f;
      #pragma unroll
      for (int mt = 0; mt < 2; ++mt)
        #pragma unroll
        for (int i = 0; i < 4; ++i) { s[mt][i] = expf(s[mt][i] - mx); sm += s[mt][i]; }
      sm += __shfl_xor(sm, 16);
      sm += __shfl_xor(sm, 32);
      const float inv = 1.0f / sm;
      #pragma unroll
      for (int mt = 0; mt < 2; ++mt) {
        ppk[n][mt][2 * nt + 0] = pk2(s[mt][0] * inv, s[mt][1] * inv);
        ppk[n][mt][2 * nt + 1] = pk2(s[mt][2] * inv, s[mt][3] * inv);
      }
    }
  }

  // ---- V pass (normal orientation), et-split halves
  u32 vpk[4][4][2];
  #pragma unroll
  for (int eh = 0; eh < 2; ++eh) {
    floatx4 vacc[2][4];
    #pragma unroll
    for (int e2 = 0; e2 < 2; ++e2)
      #pragma unroll
      for (int nt = 0; nt < 4; ++nt) vacc[e2][nt] = zero4();
    for (int ks = 0; ks < 16; ++ks) {
      short8 wv[4];
      #pragma unroll
      for (int nt = 0; nt < 4; ++nt)
        wv[nt] = *(const short8*)(Wi + (size_t)(vb + nt * 16 + lr) * DD + ks * 32 + lg * 8);
      #pragma unroll
      for (int e2 = 0; e2 < 2; ++e2) {
        short8 exf = *(const short8*)(exC + (size_t)(lex0 + (2 * eh + e2) * 16 + lr) * DD + ks * 32 + lg * 8);
        #pragma unroll
        for (int nt = 0; nt < 4; ++nt)
          vacc[e2][nt] = MFMA16(exf, wv[nt], vacc[e2][nt]);
      }
    }
    #pragma unroll
    for (int nt = 0; nt < 4; ++nt) {
      const float bv = bi[vb + nt * 16 + lr];
      #pragma unroll
      for (int e2 = 0; e2 < 2; ++e2) {
        vpk[2 * eh + e2][nt][0] = pk2(vacc[e2][nt][0] + bv, vacc[e2][nt][1] + bv);
        vpk[2 * eh + e2][nt][1] = pk2(vacc[e2][nt][2] + bv, vacc[e2][nt][3] + bv);
      }
    }
  }

  // ---- PV per node -> aoC
  #pragma unroll
  for (int n = 0; n < 2; ++n) {
    short8 paf[2], vbf[4];
    #pragma unroll
    for (int qt = 0; qt < 2; ++qt)
      paf[qt] = frag4(pa0, pa1, hi, ppk[n][0][2*qt+0], ppk[n][0][2*qt+1],
                                    ppk[n][1][2*qt+0], ppk[n][1][2*qt+1]);
    #pragma unroll
    for (int nt = 0; nt < 4; ++nt)
      vbf[nt] = frag4(pa0, pa1, hi, vpk[2*n][nt][0], vpk[2*n][nt][1],
                                    vpk[2*n+1][nt][0], vpk[2*n+1][nt][1]);
    #pragma unroll
    for (int qt = 0; qt < 2; ++qt)
      #pragma unroll
      for (int nt = 0; nt < 4; ++nt) {
        floatx4 o = MFMA16(paf[qt], vbf[nt], zero4());
        #pragma unroll
        for (int i = 0; i < 4; ++i)
          aoC[(size_t)(lex0 + n * 32 + qt * 16 + lg * 4 + i) * DD + w * 64 + nt * 16 + lr] = f2bf(o[i]);
      }
  }
}

// ============================================================================
// K3: h = gelu(AO @ Wo^T + bo), weighted-mean agg, atomic scatter.
// 256 thr / 4 waves; 2 nodes (64 edges). Zero LDS.
// ============================================================================
__global__ __launch_bounds__(256, 3) void k3_out(
    const ushort* __restrict__ aoC, const int* __restrict__ e,
    const ushort* __restrict__ Wo, const float* __restrict__ bo,
    float* __restrict__ out, int n0)
{
  const int m0   = (n0 + blockIdx.x * 2) * DEG;
  const int lex0 = blockIdx.x * 64;
  const int tid  = threadIdx.x;
  const int w    = tid >> 6;
  const int l    = tid & 63;
  const int lr   = l & 15;
  const int lg   = l >> 4;

  for (int p = 0; p < 2; ++p) {
    const int cb = w * 128 + p * 64;
    floatx4 h3[4][4];
    #pragma unroll
    for (int mt = 0; mt < 4; ++mt)
      #pragma unroll
      for (int nt = 0; nt < 4; ++nt) h3[mt][nt] = zero4();
    for (int ks = 0; ks < 16; ++ks) {
      short8 bfr[4];
      #pragma unroll
      for (int nt = 0; nt < 4; ++nt)
        bfr[nt] = *(const short8*)(Wo + (size_t)(cb + nt * 16 + lr) * DD + ks * 32 + lg * 8);
      #pragma unroll
      for (int mt = 0; mt < 4; ++mt) {
        short8 af = *(const short8*)(aoC + (size_t)(lex0 + mt * 16 + lr) * DD + ks * 32 + lg * 8);
        #pragma unroll
        for (int nt = 0; nt < 4; ++nt)
          h3[mt][nt] = MFMA16(af, bfr[nt], h3[mt][nt]);
      }
    }
    #pragma unroll
    for (int nt = 0; nt < 4; ++nt) {
      const float bias = bo[cb + nt * 16 + lr];
      #pragma unroll
      for (int mt = 0; mt < 4; ++mt)
        #pragma unroll
        for (int i = 0; i < 4; ++i)
          h3[mt][nt][i] = gelu_f(h3[mt][nt][i] + bias);
    }
    float lgA[4][4];
    #pragma unroll
    for (int mt = 0; mt < 4; ++mt)
      #pragma unroll
      for (int i = 0; i < 4; ++i) {
        float tA = h3[mt][2][i] + h3[mt][3][i];
        #pragma unroll
        for (int d2 = 1; d2 < 16; d2 <<= 1) tA += __shfl_xor(tA, d2);
        lgA[mt][i] = tA * (1.0f / 32.0f);
      }
    float eAv[4][4], iA[2];
    #pragma unroll
    for (int n = 0; n < 2; ++n) {
      float mx = -1e30f;
      #pragma unroll
      for (int m2 = 0; m2 < 2; ++m2)
        #pragma unroll
        for (int i = 0; i < 4; ++i) mx = fmaxf(mx, lgA[2*n + m2][i]);
      mx = fmaxf(mx, __shfl_xor(mx, 16));
      mx = fmaxf(mx, __shfl_xor(mx, 32));
      float sA = 0.f;
      #pragma unroll
      for (int m2 = 0; m2 < 2; ++m2)
        #pragma unroll
        for (int i = 0; i < 4; ++i) {
          eAv[2*n + m2][i] = expf(lgA[2*n + m2][i] - mx);
          sA += eAv[2*n + m2][i];
        }
      sA += __shfl_xor(sA, 16);
      sA += __shfl_xor(sA, 32);
      iA[n] = 1.0f / sA;
    }
    #pragma unroll
    for (int mt = 0; mt < 4; ++mt)
      #pragma unroll
      for (int i = 0; i < 4; ++i) {
        const int r  = mt * 16 + lg * 4 + i;
        const int d1 = e[MEDGE + m0 + r];
        float* bp = out + (size_t)d1 * 256 + (2 * w + p) * 32;
        const float aA = eAv[mt][i] * iA[mt >> 1];
        atomicAdd(bp + lr,      h3[mt][0][i] * aA);
        atomicAdd(bp + 16 + lr, h3[mt][1][i] * aA);
      }
  }
}

// fp32 -> bf16 weight pre-convert (4 elems/thread)
__global__ __launch_bounds__(256) void cvt_w(const float* __restrict__ src,
                                             ushort* __restrict__ dst, int n4)
{
  const int i = blockIdx.x * 256 + threadIdx.x;
  if (i < n4) {
    floatx4 v = *(const floatx4*)(src + (size_t)i * 4);
    short4v r;
    #pragma unroll
    for (int j = 0; j < 4; ++j) r[j] = (short)f2bf(v[j]);
    *(short4v*)(dst + (size_t)i * 4) = r;
  }
}

// ws layout (bf16 elements for weights)
#define WS_WC 0
#define WS_WI (WS_WC + 512*KC)
#define WS_WO (WS_WI + 1536*DD)
#define WS_WEND (WS_WO + 512*DD)

extern "C" void kernel_launch(void* const* d_in, const int* in_sizes, int n_in,
                              void* d_out, int out_size, void* d_ws, size_t ws_size,
                              hipStream_t stream)
{
  (void)in_sizes; (void)n_in;
  const float* x  = (const float*)d_in[0];
  const float* ea = (const float*)d_in[1];
  const int*   e  = (const int*)d_in[2];
  const float* Wc = (const float*)d_in[3];
  const float* bc = (const float*)d_in[4];
  const float* Wi = (const float*)d_in[5];
  const float* bi = (const float*)d_in[6];
  const float* Wo = (const float*)d_in[7];
  const float* bo = (const float*)d_in[8];

  ushort* wsb = (ushort*)d_ws;
  ushort* Wcb = wsb + WS_WC;
  ushort* Wib = wsb + WS_WI;
  ushort* Wob = wsb + WS_WO;

  cvt_w<<<dim3((512 * KC / 4 + 255) / 256), dim3(256), 0, stream>>>(Wc, Wcb, 512 * KC / 4);
  cvt_w<<<dim3((1536 * DD / 4 + 255) / 256), dim3(256), 0, stream>>>(Wi, Wib, 1536 * DD / 4);
  cvt_w<<<dim3((512 * DD / 4 + 255) / 256), dim3(256), 0, stream>>>(Wo, Wob, 512 * DD / 4);

  float* out = (float*)d_out;
  hipMemsetAsync(out, 0, (size_t)out_size * sizeof(float), stream);

  // chunk sizing from ws_size: ex + ao = 2 * C*32*512*2 bytes
  size_t wbytes = ((size_t)WS_WEND * 2 + 255) & ~(size_t)255;
  size_t avail  = ws_size > wbytes ? ws_size - wbytes : 0;
  long long Cll = (long long)(avail / 131072);      // bytes per node (ex+ao)
  int C = (int)(Cll > 2048 ? 2048 : Cll);           // cap for L3 residency
  C &= ~1;
  if (C < 2) C = 2;

  ushort* exC = (ushort*)((char*)d_ws + wbytes);

  for (int n0 = 0; n0 < NNODE; n0 += C) {
    int cc = NNODE - n0 < C ? NNODE - n0 : C;
    ushort* aoC = exC + (size_t)C * 32 * DD;   // fixed offset (C-based)
    k1_ex <<<dim3(cc / 2), dim3(256), 0, stream>>>(x, ea, e, Wcb, bc, exC, n0);
    k2_attn<<<dim3(cc / 2), dim3(512), 0, stream>>>(exC, Wib, bi, aoC, n0);
    k3_out <<<dim3(cc / 2), dim3(256), 0, stream>>>(aoC, e, Wob, bo, out, n0);
  }
}

// Round 8
// 5323.773 us; speedup vs baseline: 1.4850x; 1.4850x over previous
//
#include <hip/hip_runtime.h>
#include <hip/hip_bf16.h>

#define NNODE 8192
#define DEG   32
#define DIN   256
#define EDIM  64
#define KC    576            // 2*DIN + EDIM
#define DD    512            // internal width D
#define MEDGE (NNODE*DEG)

typedef __attribute__((ext_vector_type(8))) short short8;
typedef __attribute__((ext_vector_type(4))) short short4v;
typedef __attribute__((ext_vector_type(4))) float floatx4;
typedef __attribute__((ext_vector_type(4))) unsigned int uint4v;
typedef unsigned int u32;

__device__ __forceinline__ ushort f2bf(float f) {
  union { float f; unsigned int i; } v; v.f = f;
  return (ushort)((v.i + 0x7fffu + ((v.i >> 16) & 1u)) >> 16);
}
__device__ __forceinline__ u32 pk2(float a, float b) {
  return (u32)f2bf(a) | ((u32)f2bf(b) << 16);
}
__device__ __forceinline__ float gelu_f(float z) {
  return 0.5f * z * (1.0f + erff(z * 0.70710678118654752f));
}
__device__ __forceinline__ floatx4 zero4() { floatx4 v = {0.f, 0.f, 0.f, 0.f}; return v; }

__device__ __forceinline__ short8 ld_cvt8(const float* __restrict__ p) {
  floatx4 a = *(const floatx4*)(p);
  floatx4 b = *(const floatx4*)(p + 4);
  short8 r;
  r[0] = (short)f2bf(a[0]); r[1] = (short)f2bf(a[1]);
  r[2] = (short)f2bf(a[2]); r[3] = (short)f2bf(a[3]);
  r[4] = (short)f2bf(b[0]); r[5] = (short)f2bf(b[1]);
  r[6] = (short)f2bf(b[2]); r[7] = (short)f2bf(b[3]);
  return r;
}

#define MFMA16(a, b, c) __builtin_amdgcn_mfma_f32_16x16x32_bf16((a), (b), (c), 0, 0, 0)

// D-layout -> A/B-frag-layout in-register transform (verified r2-r7).
__device__ __forceinline__ u32 bpsel(int a, u32 v0, u32 v1, bool hi) {
  u32 x0 = (u32)__builtin_amdgcn_ds_bpermute(a, (int)v0);
  u32 x1 = (u32)__builtin_amdgcn_ds_bpermute(a, (int)v1);
  return hi ? x1 : x0;
}
__device__ __forceinline__ short8 frag4(int a0, int a1, bool hi,
                                        u32 t00, u32 t01, u32 t10, u32 t11) {
  uint4v r;
  r[0] = bpsel(a0, t00, t10, hi);
  r[1] = bpsel(a0, t01, t11, hi);
  r[2] = bpsel(a1, t00, t10, hi);
  r[3] = bpsel(a1, t01, t11, hi);
  union { uint4v u; short8 s; } c; c.u = r; return c.s;
}

// ============================================================================
// K0: P12 = X @ [Wc1^T | Wc2^T]  (f32 out, no bias/act).  8192x1024, K=256.
// grid (128, 4): blockIdx.y in {0,1}->P1 (k 0..255), {2,3}->P2 (k 256..511).
// ============================================================================
__global__ __launch_bounds__(256, 3) void k0_p12(
    const float* __restrict__ x, const ushort* __restrict__ Wcb,
    float* __restrict__ P12)
{
  const int r0   = blockIdx.x * 64;
  const int cbB  = blockIdx.y * 256;
  const int koff = (blockIdx.y >= 2) ? 256 : 0;
  const int tid = threadIdx.x;
  const int w = tid >> 6, l = tid & 63, lr = l & 15, lg = l >> 4;
  const int cb = cbB + w * 64;

  floatx4 acc[4][4];
  #pragma unroll
  for (int mt = 0; mt < 4; ++mt)
    #pragma unroll
    for (int nt = 0; nt < 4; ++nt) acc[mt][nt] = zero4();

  for (int ks = 0; ks < 8; ++ks) {
    short8 bfr[4];
    #pragma unroll
    for (int nt = 0; nt < 4; ++nt)
      bfr[nt] = *(const short8*)(Wcb + (size_t)((cb + nt * 16 + lr) & 511) * KC + koff + ks * 32 + lg * 8);
    #pragma unroll
    for (int mt = 0; mt < 4; ++mt) {
      short8 af = ld_cvt8(x + (size_t)(r0 + mt * 16 + lr) * DIN + ks * 32 + lg * 8);
      #pragma unroll
      for (int nt = 0; nt < 4; ++nt)
        acc[mt][nt] = MFMA16(af, bfr[nt], acc[mt][nt]);
    }
  }
  #pragma unroll
  for (int mt = 0; mt < 4; ++mt)
    #pragma unroll
    for (int nt = 0; nt < 4; ++nt)
      #pragma unroll
      for (int i = 0; i < 4; ++i)
        P12[(size_t)(r0 + mt * 16 + lg * 4 + i) * 1024 + cb + nt * 16 + lr] = acc[mt][nt][i];
}

// ============================================================================
// K1: ex = gelu(gelu(P1[src] + P2[dst] + ea@Wc3^T + bc)) -> exC [edge][512]
// block 256 thr / 4 waves, 2 nodes (64 edges). Zero LDS.
// ============================================================================
__global__ __launch_bounds__(256, 3) void k1_ex(
    const float* __restrict__ ea, const int* __restrict__ e,
    const ushort* __restrict__ Wcb, const float* __restrict__ bc,
    const float* __restrict__ P12,
    ushort* __restrict__ exC, int n0)
{
  const int m0  = (n0 + blockIdx.x * 2) * DEG;
  const int le0 = blockIdx.x * 64;
  const int tid = threadIdx.x;
  const int w = tid >> 6, l = tid & 63, lr = l & 15, lg = l >> 4;

  const int sn0 = e[m0];
  const int sn1 = e[m0 + DEG];

  for (int p = 0; p < 2; ++p) {
    const int cb = w * 128 + p * 64;
    floatx4 acc[4][4];
    #pragma unroll
    for (int et = 0; et < 4; ++et)
      #pragma unroll
      for (int nt = 0; nt < 4; ++nt) acc[et][nt] = zero4();

    #pragma unroll
    for (int s = 0; s < 2; ++s) {
      short8 bfr[4];
      #pragma unroll
      for (int nt = 0; nt < 4; ++nt)
        bfr[nt] = *(const short8*)(Wcb + (size_t)(cb + nt * 16 + lr) * KC + 512 + s * 32 + lg * 8);
      #pragma unroll
      for (int et = 0; et < 4; ++et) {
        short8 af = ld_cvt8(ea + (size_t)(m0 + et * 16 + lr) * EDIM + s * 32 + lg * 8);
        #pragma unroll
        for (int nt = 0; nt < 4; ++nt)
          acc[et][nt] = MFMA16(af, bfr[nt], acc[et][nt]);
      }
    }
    #pragma unroll
    for (int et = 0; et < 4; ++et) {
      const int sn = (et < 2) ? sn0 : sn1;
      const float* p1r = P12 + (size_t)sn * 1024;
      #pragma unroll
      for (int i = 0; i < 4; ++i) {
        const int row = et * 16 + lg * 4 + i;
        const int dn  = e[MEDGE + m0 + row];
        const float* p2r = P12 + (size_t)dn * 1024 + 512;
        #pragma unroll
        for (int nt = 0; nt < 4; ++nt) {
          const int col = cb + nt * 16 + lr;
          const float v = acc[et][nt][i] + p1r[col] + p2r[col] + bc[col];
          exC[(size_t)(le0 + row) * DD + col] = f2bf(gelu_f(gelu_f(v)));
        }
      }
    }
  }
}

// ============================================================================
// K2a: QKV GEMM. 512 thr / 8 waves, wave = head; 2 nodes (64 edges) per block.
// Q,K -> [h][edge][64] (normal);  V -> [h][ch][edge] (transposed). Zero LDS.
// ============================================================================
__global__ __launch_bounds__(512, 3) void k2a_qkv(
    const ushort* __restrict__ exC, const ushort* __restrict__ Wib,
    const float* __restrict__ bi,
    ushort* __restrict__ Qn, ushort* __restrict__ Kn, ushort* __restrict__ Vt,
    int EC)
{
  const int le0 = blockIdx.x * 64;
  const int tid = threadIdx.x;
  const int w = tid >> 6, l = tid & 63, lr = l & 15, lg = l >> 4;

  // ---- Q and K passes (normal: D rows = edges, cols = channels)
  #pragma unroll
  for (int qk = 0; qk < 2; ++qk) {
    const int rb = qk ? (512 + w * 64) : (w * 64);
    ushort* __restrict__ Dst = qk ? Kn : Qn;
    #pragma unroll
    for (int eh = 0; eh < 2; ++eh) {
      floatx4 acc[2][4];
      #pragma unroll
      for (int e2 = 0; e2 < 2; ++e2)
        #pragma unroll
        for (int nt = 0; nt < 4; ++nt) acc[e2][nt] = zero4();
      for (int ks = 0; ks < 16; ++ks) {
        short8 wf[4];
        #pragma unroll
        for (int nt = 0; nt < 4; ++nt)
          wf[nt] = *(const short8*)(Wib + (size_t)(rb + nt * 16 + lr) * DD + ks * 32 + lg * 8);
        #pragma unroll
        for (int e2 = 0; e2 < 2; ++e2) {
          short8 exf = *(const short8*)(exC + (size_t)(le0 + (eh * 2 + e2) * 16 + lr) * DD + ks * 32 + lg * 8);
          #pragma unroll
          for (int nt = 0; nt < 4; ++nt)
            acc[e2][nt] = MFMA16(exf, wf[nt], acc[e2][nt]);
        }
      }
      #pragma unroll
      for (int nt = 0; nt < 4; ++nt) {
        const float bias = bi[rb + nt * 16 + lr];
        #pragma unroll
        for (int e2 = 0; e2 < 2; ++e2)
          #pragma unroll
          for (int i = 0; i < 4; ++i)
            Dst[(size_t)w * EC * 64 +
                (size_t)(le0 + (eh * 2 + e2) * 16 + lg * 4 + i) * 64 + nt * 16 + lr] =
                f2bf(acc[e2][nt][i] + bias);
      }
    }
  }

  // ---- V pass (transposed: D rows = v-channels, cols = edges)
  #pragma unroll
  for (int mh = 0; mh < 2; ++mh) {
    floatx4 acc[2][4];
    #pragma unroll
    for (int m2 = 0; m2 < 2; ++m2)
      #pragma unroll
      for (int et = 0; et < 4; ++et) acc[m2][et] = zero4();
    for (int ks = 0; ks < 16; ++ks) {
      short8 wf[2];
      #pragma unroll
      for (int m2 = 0; m2 < 2; ++m2)
        wf[m2] = *(const short8*)(Wib + (size_t)(1024 + w * 64 + (mh * 2 + m2) * 16 + lr) * DD + ks * 32 + lg * 8);
      #pragma unroll
      for (int et = 0; et < 4; ++et) {
        short8 exf = *(const short8*)(exC + (size_t)(le0 + et * 16 + lr) * DD + ks * 32 + lg * 8);
        #pragma unroll
        for (int m2 = 0; m2 < 2; ++m2)
          acc[m2][et] = MFMA16(wf[m2], exf, acc[m2][et]);
      }
    }
    #pragma unroll
    for (int m2 = 0; m2 < 2; ++m2)
      #pragma unroll
      for (int i = 0; i < 4; ++i) {
        const int vc = (mh * 2 + m2) * 16 + lg * 4 + i;
        const float bias = bi[1024 + w * 64 + vc];
        #pragma unroll
        for (int et = 0; et < 4; ++et)
          Vt[(size_t)w * 64 * EC + (size_t)vc * EC + le0 + et * 16 + lr] =
              f2bf(acc[m2][et][i] + bias);
      }
  }
}

// ============================================================================
// K2b: attention. 512 thr / 8 waves, wave = head; 2 nodes per block.
// Direct A/B-frag loads from Qn/Kn/Vt; frag4 only for the P transpose.
// ============================================================================
__global__ __launch_bounds__(512, 3) void k2b_attn(
    const ushort* __restrict__ Qn, const ushort* __restrict__ Kn,
    const ushort* __restrict__ Vt,
    ushort* __restrict__ aoC, int EC)
{
  const int le0 = blockIdx.x * 64;
  const int tid = threadIdx.x;
  const int w = tid >> 6, l = tid & 63, lr = l & 15, lg = l >> 4;

  const ushort* Qh = Qn + (size_t)w * EC * 64;
  const ushort* Kh = Kn + (size_t)w * EC * 64;
  const ushort* Vh = Vt + (size_t)w * 64 * EC;

  const int pa0 = ((2 * (lg & 1)) * 16 + lr) * 4;
  const int pa1 = pa0 + 64;
  const bool hi = ((lg >> 1) & 1) != 0;

  #pragma unroll
  for (int n = 0; n < 2; ++n) {
    const int e0 = le0 + n * 32;

    // scores[kedge][qedge]: A = K rows=ke, B = Q cols=qe (both contiguous 16B)
    floatx4 sacc[2][2];
    #pragma unroll
    for (int a = 0; a < 2; ++a)
      #pragma unroll
      for (int b = 0; b < 2; ++b) sacc[a][b] = zero4();
    #pragma unroll
    for (int ks2 = 0; ks2 < 2; ++ks2) {
      short8 kfr[2], qfr[2];
      #pragma unroll
      for (int mt = 0; mt < 2; ++mt)
        kfr[mt] = *(const short8*)(Kh + (size_t)(e0 + mt * 16 + lr) * 64 + ks2 * 32 + lg * 8);
      #pragma unroll
      for (int nt = 0; nt < 2; ++nt)
        qfr[nt] = *(const short8*)(Qh + (size_t)(e0 + nt * 16 + lr) * 64 + ks2 * 32 + lg * 8);
      #pragma unroll
      for (int mt = 0; mt < 2; ++mt)
        #pragma unroll
        for (int nt = 0; nt < 2; ++nt)
          sacc[mt][nt] = MFMA16(kfr[mt], qfr[nt], sacc[mt][nt]);
    }

    // softmax over k-edges (rows): in-lane over mt,i then shfl 16,32 (verbatim r7)
    u32 ppk[2][4];
    #pragma unroll
    for (int nt = 0; nt < 2; ++nt) {
      float s[2][4];
      float mx = -1e30f;
      #pragma unroll
      for (int mt = 0; mt < 2; ++mt)
        #pragma unroll
        for (int i = 0; i < 4; ++i) {
          s[mt][i] = sacc[mt][nt][i] * 0.125f;
          mx = fmaxf(mx, s[mt][i]);
        }
      mx = fmaxf(mx, __shfl_xor(mx, 16));
      mx = fmaxf(mx, __shfl_xor(mx, 32));
      float sm = 0.f;
      #pragma unroll
      for (int mt = 0; mt < 2; ++mt)
        #pragma unroll
        for (int i = 0; i < 4; ++i) { s[mt][i] = expf(s[mt][i] - mx); sm += s[mt][i]; }
      sm += __shfl_xor(sm, 16);
      sm += __shfl_xor(sm, 32);
      const float inv = 1.0f / sm;
      #pragma unroll
      for (int mt = 0; mt < 2; ++mt) {
        ppk[mt][2 * nt + 0] = pk2(s[mt][0] * inv, s[mt][1] * inv);
        ppk[mt][2 * nt + 1] = pk2(s[mt][2] * inv, s[mt][3] * inv);
      }
    }

    // PV: A = P^T (frag4), B = V from Vt[ch][edge] contiguous
    short8 paf[2], vbf[4];
    #pragma unroll
    for (int qt = 0; qt < 2; ++qt)
      paf[qt] = frag4(pa0, pa1, hi, ppk[0][2 * qt + 0], ppk[0][2 * qt + 1],
                                    ppk[1][2 * qt + 0], ppk[1][2 * qt + 1]);
    #pragma unroll
    for (int nt = 0; nt < 4; ++nt)
      vbf[nt] = *(const short8*)(Vh + (size_t)(nt * 16 + lr) * EC + e0 + lg * 8);
    #pragma unroll
    for (int qt = 0; qt < 2; ++qt)
      #pragma unroll
      for (int nt = 0; nt < 4; ++nt) {
        floatx4 o = MFMA16(paf[qt], vbf[nt], zero4());
        #pragma unroll
        for (int i = 0; i < 4; ++i)
          aoC[(size_t)(e0 + qt * 16 + lg * 4 + i) * DD + w * 64 + nt * 16 + lr] = f2bf(o[i]);
      }
  }
}

// ============================================================================
// K3: h = gelu(AO @ Wo^T + bo), weighted-mean agg, atomic scatter. (r7 verbatim)
// ============================================================================
__global__ __launch_bounds__(256, 3) void k3_out(
    const ushort* __restrict__ aoC, const int* __restrict__ e,
    const ushort* __restrict__ Wo, const float* __restrict__ bo,
    float* __restrict__ out, int n0)
{
  const int m0   = (n0 + blockIdx.x * 2) * DEG;
  const int lex0 = blockIdx.x * 64;
  const int tid  = threadIdx.x;
  const int w = tid >> 6, l = tid & 63, lr = l & 15, lg = l >> 4;

  for (int p = 0; p < 2; ++p) {
    const int cb = w * 128 + p * 64;
    floatx4 h3[4][4];
    #pragma unroll
    for (int mt = 0; mt < 4; ++mt)
      #pragma unroll
      for (int nt = 0; nt < 4; ++nt) h3[mt][nt] = zero4();
    for (int ks = 0; ks < 16; ++ks) {
      short8 bfr[4];
      #pragma unroll
      for (int nt = 0; nt < 4; ++nt)
        bfr[nt] = *(const short8*)(Wo + (size_t)(cb + nt * 16 + lr) * DD + ks * 32 + lg * 8);
      #pragma unroll
      for (int mt = 0; mt < 4; ++mt) {
        short8 af = *(const short8*)(aoC + (size_t)(lex0 + mt * 16 + lr) * DD + ks * 32 + lg * 8);
        #pragma unroll
        for (int nt = 0; nt < 4; ++nt)
          h3[mt][nt] = MFMA16(af, bfr[nt], h3[mt][nt]);
      }
    }
    #pragma unroll
    for (int nt = 0; nt < 4; ++nt) {
      const float bias = bo[cb + nt * 16 + lr];
      #pragma unroll
      for (int mt = 0; mt < 4; ++mt)
        #pragma unroll
        for (int i = 0; i < 4; ++i)
          h3[mt][nt][i] = gelu_f(h3[mt][nt][i] + bias);
    }
    float lgA[4][4];
    #pragma unroll
    for (int mt = 0; mt < 4; ++mt)
      #pragma unroll
      for (int i = 0; i < 4; ++i) {
        float tA = h3[mt][2][i] + h3[mt][3][i];
        #pragma unroll
        for (int d2 = 1; d2 < 16; d2 <<= 1) tA += __shfl_xor(tA, d2);
        lgA[mt][i] = tA * (1.0f / 32.0f);
      }
    float eAv[4][4], iA[2];
    #pragma unroll
    for (int n = 0; n < 2; ++n) {
      float mx = -1e30f;
      #pragma unroll
      for (int m2 = 0; m2 < 2; ++m2)
        #pragma unroll
        for (int i = 0; i < 4; ++i) mx = fmaxf(mx, lgA[2 * n + m2][i]);
      mx = fmaxf(mx, __shfl_xor(mx, 16));
      mx = fmaxf(mx, __shfl_xor(mx, 32));
      float sA = 0.f;
      #pragma unroll
      for (int m2 = 0; m2 < 2; ++m2)
        #pragma unroll
        for (int i = 0; i < 4; ++i) {
          eAv[2 * n + m2][i] = expf(lgA[2 * n + m2][i] - mx);
          sA += eAv[2 * n + m2][i];
        }
      sA += __shfl_xor(sA, 16);
      sA += __shfl_xor(sA, 32);
      iA[n] = 1.0f / sA;
    }
    #pragma unroll
    for (int mt = 0; mt < 4; ++mt)
      #pragma unroll
      for (int i = 0; i < 4; ++i) {
        const int r  = mt * 16 + lg * 4 + i;
        const int d1 = e[MEDGE + m0 + r];
        float* bp = out + (size_t)d1 * 256 + (2 * w + p) * 32;
        const float aA = eAv[mt][i] * iA[mt >> 1];
        atomicAdd(bp + lr,      h3[mt][0][i] * aA);
        atomicAdd(bp + 16 + lr, h3[mt][1][i] * aA);
      }
  }
}

// fp32 -> bf16 weight pre-convert
__global__ __launch_bounds__(256) void cvt_w(const float* __restrict__ src,
                                             ushort* __restrict__ dst, int n4)
{
  const int i = blockIdx.x * 256 + threadIdx.x;
  if (i < n4) {
    floatx4 v = *(const floatx4*)(src + (size_t)i * 4);
    short4v r;
    #pragma unroll
    for (int j = 0; j < 4; ++j) r[j] = (short)f2bf(v[j]);
    *(short4v*)(dst + (size_t)i * 4) = r;
  }
}

// ws layout: weights bf16 (2686976 B) | P12 f32 (33554432 B) | chunk buffers
#define WS_WC 0
#define WS_WI (WS_WC + 512*KC)
#define WS_WO (WS_WI + 1536*DD)
#define WB_BYTES   2686976
#define P12_BYTES  33554432
#define CHUNK_OFF  (WB_BYTES + P12_BYTES)

extern "C" void kernel_launch(void* const* d_in, const int* in_sizes, int n_in,
                              void* d_out, int out_size, void* d_ws, size_t ws_size,
                              hipStream_t stream)
{
  (void)in_sizes; (void)n_in;
  const float* x  = (const float*)d_in[0];
  const float* ea = (const float*)d_in[1];
  const int*   e  = (const int*)d_in[2];
  const float* Wc = (const float*)d_in[3];
  const float* bc = (const float*)d_in[4];
  const float* Wi = (const float*)d_in[5];
  const float* bi = (const float*)d_in[6];
  const float* Wo = (const float*)d_in[7];
  const float* bo = (const float*)d_in[8];

  ushort* wsb = (ushort*)d_ws;
  ushort* Wcb = wsb + WS_WC;
  ushort* Wib = wsb + WS_WI;
  ushort* Wob = wsb + WS_WO;
  float*  P12 = (float*)((char*)d_ws + WB_BYTES);

  cvt_w<<<dim3((512 * KC / 4 + 255) / 256), dim3(256), 0, stream>>>(Wc, Wcb, 512 * KC / 4);
  cvt_w<<<dim3((1536 * DD / 4 + 255) / 256), dim3(256), 0, stream>>>(Wi, Wib, 1536 * DD / 4);
  cvt_w<<<dim3((512 * DD / 4 + 255) / 256), dim3(256), 0, stream>>>(Wo, Wob, 512 * DD / 4);

  k0_p12<<<dim3(128, 4), dim3(256), 0, stream>>>(x, Wcb, P12);

  float* out = (float*)d_out;
  hipMemsetAsync(out, 0, (size_t)out_size * sizeof(float), stream);

  // chunk sizing: 5 buffers (ex, Qn, Kn, Vt, AO), each C*32768 bytes
  size_t avail = ws_size > (size_t)CHUNK_OFF ? ws_size - (size_t)CHUNK_OFF : 0;
  long long Cll = (long long)(avail / 163840);
  int C = (int)(Cll > 2048 ? 2048 : Cll);
  C &= ~1;
  if (C < 2) C = 2;
  const size_t seg = (size_t)C * 32768;
  char* cbase = (char*)d_ws + CHUNK_OFF;
  ushort* exC = (ushort*)(cbase);
  ushort* Qn  = (ushort*)(cbase + seg);
  ushort* Kn  = (ushort*)(cbase + 2 * seg);
  ushort* Vt  = (ushort*)(cbase + 3 * seg);
  ushort* AO  = (ushort*)(cbase + 4 * seg);
  const int EC = C * 32;

  for (int n0 = 0; n0 < NNODE; n0 += C) {
    const int cc = (NNODE - n0 < C) ? (NNODE - n0) : C;
    k1_ex  <<<dim3(cc / 2), dim3(256), 0, stream>>>(ea, e, Wcb, bc, P12, exC, n0);
    k2a_qkv<<<dim3(cc / 2), dim3(512), 0, stream>>>(exC, Wib, bi, Qn, Kn, Vt, EC);
    k2b_attn<<<dim3(cc / 2), dim3(512), 0, stream>>>(Qn, Kn, Vt, AO, EC);
    k3_out <<<dim3(cc / 2), dim3(256), 0, stream>>>(AO, e, Wob, bo, out, n0);
  }
}

// Round 9
// 2689.140 us; speedup vs baseline: 2.9399x; 1.9797x over previous
//
#include <hip/hip_runtime.h>
#include <hip/hip_bf16.h>

#define NNODE 8192
#define DEG   32
#define DIN   256
#define EDIM  64
#define KC    576            // 2*DIN + EDIM
#define DD    512            // internal width D
#define MEDGE (NNODE*DEG)

typedef __attribute__((ext_vector_type(8))) short short8;
typedef __attribute__((ext_vector_type(4))) short short4v;
typedef __attribute__((ext_vector_type(4))) float floatx4;
typedef __attribute__((ext_vector_type(4))) unsigned int uint4v;
typedef unsigned int u32;

__device__ __forceinline__ ushort f2bf(float f) {
  union { float f; unsigned int i; } v; v.f = f;
  return (ushort)((v.i + 0x7fffu + ((v.i >> 16) & 1u)) >> 16);
}
__device__ __forceinline__ u32 pk2(float a, float b) {
  return (u32)f2bf(a) | ((u32)f2bf(b) << 16);
}
__device__ __forceinline__ float gelu_f(float z) {
  return 0.5f * z * (1.0f + erff(z * 0.70710678118654752f));
}
__device__ __forceinline__ floatx4 zero4() { floatx4 v = {0.f, 0.f, 0.f, 0.f}; return v; }

__device__ __forceinline__ short8 ld_cvt8(const float* __restrict__ p) {
  floatx4 a = *(const floatx4*)(p);
  floatx4 b = *(const floatx4*)(p + 4);
  short8 r;
  r[0] = (short)f2bf(a[0]); r[1] = (short)f2bf(a[1]);
  r[2] = (short)f2bf(a[2]); r[3] = (short)f2bf(a[3]);
  r[4] = (short)f2bf(b[0]); r[5] = (short)f2bf(b[1]);
  r[6] = (short)f2bf(b[2]); r[7] = (short)f2bf(b[3]);
  return r;
}

#define MFMA16(a, b, c) __builtin_amdgcn_mfma_f32_16x16x32_bf16((a), (b), (c), 0, 0, 0)

// D-layout -> A/B-frag-layout in-register transform (verified r2-r8).
__device__ __forceinline__ u32 bpsel(int a, u32 v0, u32 v1, bool hi) {
  u32 x0 = (u32)__builtin_amdgcn_ds_bpermute(a, (int)v0);
  u32 x1 = (u32)__builtin_amdgcn_ds_bpermute(a, (int)v1);
  return hi ? x1 : x0;
}
__device__ __forceinline__ short8 frag4(int a0, int a1, bool hi,
                                        u32 t00, u32 t01, u32 t10, u32 t11) {
  uint4v r;
  r[0] = bpsel(a0, t00, t10, hi);
  r[1] = bpsel(a0, t01, t11, hi);
  r[2] = bpsel(a1, t00, t10, hi);
  r[3] = bpsel(a1, t01, t11, hi);
  union { uint4v u; short8 s; } c; c.u = r; return c.s;
}

// async global -> LDS, 16 bytes per lane (wave-uniform LDS base + lane*16)
__device__ __forceinline__ void gl_lds16(const void* g, void* l) {
  __builtin_amdgcn_global_load_lds(
      (const __attribute__((address_space(1))) void*)g,
      (__attribute__((address_space(3))) void*)l,
      16, 0, 0);
}

// stage a [128 rows][64 k] bf16 tile (16 KB) from a row-pitch-512-elem matrix
// gbase points at (row0, k0) already. 256 threads, 4 calls each.
__device__ __forceinline__ void stage_tile(const ushort* gbase, ushort* sdst, int tid) {
  #pragma unroll
  for (int j = 0; j < 4; ++j) {
    const int off = (j * 256 + tid) * 16;   // byte offset in tile
    const int row = off >> 7;               // /128 (row = 128 B)
    const int kb  = off & 127;
    const char* g = (const char*)gbase + (size_t)row * 1024 + kb;
    char* l = (char*)sdst + j * 4096 + (tid >> 6) * 1024;   // wave-uniform
    gl_lds16(g, l);
  }
}

// ============================================================================
// K0: P12 = X @ [Wc1^T | Wc2^T]  (f32 out, no bias/act).  8192x1024, K=256.
// ============================================================================
__global__ __launch_bounds__(256, 3) void k0_p12(
    const float* __restrict__ x, const ushort* __restrict__ Wcb,
    float* __restrict__ P12)
{
  const int r0   = blockIdx.x * 64;
  const int cbB  = blockIdx.y * 256;
  const int koff = (blockIdx.y >= 2) ? 256 : 0;
  const int tid = threadIdx.x;
  const int w = tid >> 6, l = tid & 63, lr = l & 15, lg = l >> 4;
  const int cb = cbB + w * 64;

  floatx4 acc[4][4];
  #pragma unroll
  for (int mt = 0; mt < 4; ++mt)
    #pragma unroll
    for (int nt = 0; nt < 4; ++nt) acc[mt][nt] = zero4();

  for (int ks = 0; ks < 8; ++ks) {
    short8 bfr[4];
    #pragma unroll
    for (int nt = 0; nt < 4; ++nt)
      bfr[nt] = *(const short8*)(Wcb + (size_t)((cb + nt * 16 + lr) & 511) * KC + koff + ks * 32 + lg * 8);
    #pragma unroll
    for (int mt = 0; mt < 4; ++mt) {
      short8 af = ld_cvt8(x + (size_t)(r0 + mt * 16 + lr) * DIN + ks * 32 + lg * 8);
      #pragma unroll
      for (int nt = 0; nt < 4; ++nt)
        acc[mt][nt] = MFMA16(af, bfr[nt], acc[mt][nt]);
    }
  }
  #pragma unroll
  for (int mt = 0; mt < 4; ++mt)
    #pragma unroll
    for (int nt = 0; nt < 4; ++nt)
      #pragma unroll
      for (int i = 0; i < 4; ++i)
        P12[(size_t)(r0 + mt * 16 + lg * 4 + i) * 1024 + cb + nt * 16 + lr] = acc[mt][nt][i];
}

// ============================================================================
// K1: ex = gelu(gelu(P1[src] + P2[dst] + ea@Wc3^T + bc)) -> exC [edge][512]
// (r8 verbatim)
// ============================================================================
__global__ __launch_bounds__(256, 3) void k1_ex(
    const float* __restrict__ ea, const int* __restrict__ e,
    const ushort* __restrict__ Wcb, const float* __restrict__ bc,
    const float* __restrict__ P12,
    ushort* __restrict__ exC, int n0)
{
  const int m0  = (n0 + blockIdx.x * 2) * DEG;
  const int le0 = blockIdx.x * 64;
  const int tid = threadIdx.x;
  const int w = tid >> 6, l = tid & 63, lr = l & 15, lg = l >> 4;

  const int sn0 = e[m0];
  const int sn1 = e[m0 + DEG];

  for (int p = 0; p < 2; ++p) {
    const int cb = w * 128 + p * 64;
    floatx4 acc[4][4];
    #pragma unroll
    for (int et = 0; et < 4; ++et)
      #pragma unroll
      for (int nt = 0; nt < 4; ++nt) acc[et][nt] = zero4();

    #pragma unroll
    for (int s = 0; s < 2; ++s) {
      short8 bfr[4];
      #pragma unroll
      for (int nt = 0; nt < 4; ++nt)
        bfr[nt] = *(const short8*)(Wcb + (size_t)(cb + nt * 16 + lr) * KC + 512 + s * 32 + lg * 8);
      #pragma unroll
      for (int et = 0; et < 4; ++et) {
        short8 af = ld_cvt8(ea + (size_t)(m0 + et * 16 + lr) * EDIM + s * 32 + lg * 8);
        #pragma unroll
        for (int nt = 0; nt < 4; ++nt)
          acc[et][nt] = MFMA16(af, bfr[nt], acc[et][nt]);
      }
    }
    #pragma unroll
    for (int et = 0; et < 4; ++et) {
      const int sn = (et < 2) ? sn0 : sn1;
      const float* p1r = P12 + (size_t)sn * 1024;
      #pragma unroll
      for (int i = 0; i < 4; ++i) {
        const int row = et * 16 + lg * 4 + i;
        const int dn  = e[MEDGE + m0 + row];
        const float* p2r = P12 + (size_t)dn * 1024 + 512;
        #pragma unroll
        for (int nt = 0; nt < 4; ++nt) {
          const int col = cb + nt * 16 + lr;
          const float v = acc[et][nt][i] + p1r[col] + p2r[col] + bc[col];
          exC[(size_t)(le0 + row) * DD + col] = f2bf(gelu_f(gelu_f(v)));
        }
      }
    }
  }
}

// ============================================================================
// K2a (NEW, m97-style tiled GEMM): QKV = exC @ Wi^T.
// grid (EC/128, 12); 256 thr / 4 waves; 128x128 tile, K=512 in 8 steps.
// Epilogue: Q,K -> [h][edge][64]; V -> [h][ch][edge].
// ============================================================================
__global__ __launch_bounds__(256) void k2a_qkv(
    const ushort* __restrict__ exC, const ushort* __restrict__ Wib,
    const float* __restrict__ bi,
    ushort* __restrict__ Qn, ushort* __restrict__ Kn, ushort* __restrict__ Vt,
    int EC)
{
  __shared__ __align__(16) ushort sA[128 * 64];
  __shared__ __align__(16) ushort sB[128 * 64];

  const int bx   = blockIdx.x;     // M-tile: 128 edges
  const int nt12 = blockIdx.y;     // N-tile: 128 of 1536 out-cols
  const int tid = threadIdx.x;
  const int w = tid >> 6, l = tid & 63, lr = l & 15, lg = l >> 4;
  const int wm = w >> 1, wn = w & 1;

  floatx4 acc[4][4];
  #pragma unroll
  for (int mt = 0; mt < 4; ++mt)
    #pragma unroll
    for (int nt = 0; nt < 4; ++nt) acc[mt][nt] = zero4();

  const ushort* gA = exC + (size_t)bx * 128 * DD;
  const ushort* gB = Wib + (size_t)nt12 * 128 * DD;

  for (int ks = 0; ks < 8; ++ks) {
    stage_tile(gA + ks * 64, sA, tid);
    stage_tile(gB + ks * 64, sB, tid);
    __syncthreads();
    #pragma unroll
    for (int ksub = 0; ksub < 2; ++ksub) {
      short8 a[4], b[4];
      #pragma unroll
      for (int mt = 0; mt < 4; ++mt)
        a[mt] = *(const short8*)(&sA[(wm * 64 + mt * 16 + lr) * 64 + ksub * 32 + lg * 8]);
      #pragma unroll
      for (int nt = 0; nt < 4; ++nt)
        b[nt] = *(const short8*)(&sB[(wn * 64 + nt * 16 + lr) * 64 + ksub * 32 + lg * 8]);
      #pragma unroll
      for (int mt = 0; mt < 4; ++mt)
        #pragma unroll
        for (int nt = 0; nt < 4; ++nt)
          acc[mt][nt] = MFMA16(a[mt], b[nt], acc[mt][nt]);
    }
    __syncthreads();
  }

  // epilogue: wave's 64 out-cols live in exactly one (segment, head)
  const int o0    = nt12 * 128 + wn * 64;
  const int seg   = o0 >> 9;
  const int h     = (o0 >> 6) & 7;
  const int ebase = bx * 128 + wm * 64;

  if (seg < 2) {
    ushort* Dst = (seg == 0 ? Qn : Kn) + (size_t)h * EC * 64;
    #pragma unroll
    for (int nt = 0; nt < 4; ++nt) {
      const int ch = nt * 16 + lr;
      const float bias = bi[o0 + ch];
      #pragma unroll
      for (int mt = 0; mt < 4; ++mt)
        #pragma unroll
        for (int i = 0; i < 4; ++i)
          Dst[(size_t)(ebase + mt * 16 + lg * 4 + i) * 64 + ch] = f2bf(acc[mt][nt][i] + bias);
    }
  } else {
    ushort* Dv = Vt + (size_t)h * 64 * EC;
    #pragma unroll
    for (int nt = 0; nt < 4; ++nt) {
      const int ch = nt * 16 + lr;
      const float bias = bi[o0 + ch];
      #pragma unroll
      for (int mt = 0; mt < 4; ++mt) {
        short4v pk;
        #pragma unroll
        for (int i = 0; i < 4; ++i) pk[i] = (short)f2bf(acc[mt][nt][i] + bias);
        *(short4v*)(&Dv[(size_t)ch * EC + ebase + mt * 16 + lg * 4]) = pk;
      }
    }
  }
}

// ============================================================================
// K2b: attention (r8 verbatim). 512 thr / 8 waves, wave = head; 2 nodes/block.
// ============================================================================
__global__ __launch_bounds__(512, 3) void k2b_attn(
    const ushort* __restrict__ Qn, const ushort* __restrict__ Kn,
    const ushort* __restrict__ Vt,
    ushort* __restrict__ aoC, int EC)
{
  const int le0 = blockIdx.x * 64;
  const int tid = threadIdx.x;
  const int w = tid >> 6, l = tid & 63, lr = l & 15, lg = l >> 4;

  const ushort* Qh = Qn + (size_t)w * EC * 64;
  const ushort* Kh = Kn + (size_t)w * EC * 64;
  const ushort* Vh = Vt + (size_t)w * 64 * EC;

  const int pa0 = ((2 * (lg & 1)) * 16 + lr) * 4;
  const int pa1 = pa0 + 64;
  const bool hi = ((lg >> 1) & 1) != 0;

  #pragma unroll
  for (int n = 0; n < 2; ++n) {
    const int e0 = le0 + n * 32;

    floatx4 sacc[2][2];
    #pragma unroll
    for (int a = 0; a < 2; ++a)
      #pragma unroll
      for (int b = 0; b < 2; ++b) sacc[a][b] = zero4();
    #pragma unroll
    for (int ks2 = 0; ks2 < 2; ++ks2) {
      short8 kfr[2], qfr[2];
      #pragma unroll
      for (int mt = 0; mt < 2; ++mt)
        kfr[mt] = *(const short8*)(Kh + (size_t)(e0 + mt * 16 + lr) * 64 + ks2 * 32 + lg * 8);
      #pragma unroll
      for (int nt = 0; nt < 2; ++nt)
        qfr[nt] = *(const short8*)(Qh + (size_t)(e0 + nt * 16 + lr) * 64 + ks2 * 32 + lg * 8);
      #pragma unroll
      for (int mt = 0; mt < 2; ++mt)
        #pragma unroll
        for (int nt = 0; nt < 2; ++nt)
          sacc[mt][nt] = MFMA16(kfr[mt], qfr[nt], sacc[mt][nt]);
    }

    u32 ppk[2][4];
    #pragma unroll
    for (int nt = 0; nt < 2; ++nt) {
      float s[2][4];
      float mx = -1e30f;
      #pragma unroll
      for (int mt = 0; mt < 2; ++mt)
        #pragma unroll
        for (int i = 0; i < 4; ++i) {
          s[mt][i] = sacc[mt][nt][i] * 0.125f;
          mx = fmaxf(mx, s[mt][i]);
        }
      mx = fmaxf(mx, __shfl_xor(mx, 16));
      mx = fmaxf(mx, __shfl_xor(mx, 32));
      float sm = 0.f;
      #pragma unroll
      for (int mt = 0; mt < 2; ++mt)
        #pragma unroll
        for (int i = 0; i < 4; ++i) { s[mt][i] = expf(s[mt][i] - mx); sm += s[mt][i]; }
      sm += __shfl_xor(sm, 16);
      sm += __shfl_xor(sm, 32);
      const float inv = 1.0f / sm;
      #pragma unroll
      for (int mt = 0; mt < 2; ++mt) {
        ppk[mt][2 * nt + 0] = pk2(s[mt][0] * inv, s[mt][1] * inv);
        ppk[mt][2 * nt + 1] = pk2(s[mt][2] * inv, s[mt][3] * inv);
      }
    }

    short8 paf[2], vbf[4];
    #pragma unroll
    for (int qt = 0; qt < 2; ++qt)
      paf[qt] = frag4(pa0, pa1, hi, ppk[0][2 * qt + 0], ppk[0][2 * qt + 1],
                                    ppk[1][2 * qt + 0], ppk[1][2 * qt + 1]);
    #pragma unroll
    for (int nt = 0; nt < 4; ++nt)
      vbf[nt] = *(const short8*)(Vh + (size_t)(nt * 16 + lr) * EC + e0 + lg * 8);
    #pragma unroll
    for (int qt = 0; qt < 2; ++qt)
      #pragma unroll
      for (int nt = 0; nt < 4; ++nt) {
        floatx4 o = MFMA16(paf[qt], vbf[nt], zero4());
        #pragma unroll
        for (int i = 0; i < 4; ++i)
          aoC[(size_t)(e0 + qt * 16 + lg * 4 + i) * DD + w * 64 + nt * 16 + lr] = f2bf(o[i]);
      }
  }
}

// ============================================================================
// K3 (NEW, tiled): h = gelu(AO @ Wo^T + bo), weighted-mean agg, atomic scatter.
// grid (EC/128, 4); 256 thr / 4 waves; wave = 64 edges (2 nodes) x 64 cols (1 head).
// ============================================================================
__global__ __launch_bounds__(256) void k3_out(
    const ushort* __restrict__ aoC, const int* __restrict__ e,
    const ushort* __restrict__ Wob, const float* __restrict__ bo,
    float* __restrict__ out, int n0)
{
  __shared__ __align__(16) ushort sA[128 * 64];
  __shared__ __align__(16) ushort sB[128 * 64];

  const int bx  = blockIdx.x;     // M-tile: 128 edges = 4 nodes
  const int nt4 = blockIdx.y;     // N-tile: 128 of 512 out-cols
  const int tid = threadIdx.x;
  const int w = tid >> 6, l = tid & 63, lr = l & 15, lg = l >> 4;
  const int wm = w >> 1, wn = w & 1;

  floatx4 acc[4][4];
  #pragma unroll
  for (int mt = 0; mt < 4; ++mt)
    #pragma unroll
    for (int nt = 0; nt < 4; ++nt) acc[mt][nt] = zero4();

  const ushort* gA = aoC + (size_t)bx * 128 * DD;
  const ushort* gB = Wob + (size_t)nt4 * 128 * DD;

  for (int ks = 0; ks < 8; ++ks) {
    stage_tile(gA + ks * 64, sA, tid);
    stage_tile(gB + ks * 64, sB, tid);
    __syncthreads();
    #pragma unroll
    for (int ksub = 0; ksub < 2; ++ksub) {
      short8 a[4], b[4];
      #pragma unroll
      for (int mt = 0; mt < 4; ++mt)
        a[mt] = *(const short8*)(&sA[(wm * 64 + mt * 16 + lr) * 64 + ksub * 32 + lg * 8]);
      #pragma unroll
      for (int nt = 0; nt < 4; ++nt)
        b[nt] = *(const short8*)(&sB[(wn * 64 + nt * 16 + lr) * 64 + ksub * 32 + lg * 8]);
      #pragma unroll
      for (int mt = 0; mt < 4; ++mt)
        #pragma unroll
        for (int nt = 0; nt < 4; ++nt)
          acc[mt][nt] = MFMA16(a[mt], b[nt], acc[mt][nt]);
    }
    __syncthreads();
  }

  // epilogue: wave covers 1 head (64 cols: nt 0,1 = ch0; nt 2,3 = ch1), 2 nodes
  const int head = nt4 * 2 + wn;
  floatx4 h3[4][4];
  #pragma unroll
  for (int nt = 0; nt < 4; ++nt) {
    const float bias = bo[nt4 * 128 + wn * 64 + nt * 16 + lr];
    #pragma unroll
    for (int mt = 0; mt < 4; ++mt)
      #pragma unroll
      for (int i = 0; i < 4; ++i)
        h3[mt][nt][i] = gelu_f(acc[mt][nt][i] + bias);
  }
  float lgA[4][4];
  #pragma unroll
  for (int mt = 0; mt < 4; ++mt)
    #pragma unroll
    for (int i = 0; i < 4; ++i) {
      float tA = h3[mt][2][i] + h3[mt][3][i];
      #pragma unroll
      for (int d2 = 1; d2 < 16; d2 <<= 1) tA += __shfl_xor(tA, d2);
      lgA[mt][i] = tA * (1.0f / 32.0f);
    }
  float eAv[4][4], iA[2];
  #pragma unroll
  for (int n = 0; n < 2; ++n) {
    float mx = -1e30f;
    #pragma unroll
    for (int m2 = 0; m2 < 2; ++m2)
      #pragma unroll
      for (int i = 0; i < 4; ++i) mx = fmaxf(mx, lgA[2 * n + m2][i]);
    mx = fmaxf(mx, __shfl_xor(mx, 16));
    mx = fmaxf(mx, __shfl_xor(mx, 32));
    float sA2 = 0.f;
    #pragma unroll
    for (int m2 = 0; m2 < 2; ++m2)
      #pragma unroll
      for (int i = 0; i < 4; ++i) {
        eAv[2 * n + m2][i] = expf(lgA[2 * n + m2][i] - mx);
        sA2 += eAv[2 * n + m2][i];
      }
    sA2 += __shfl_xor(sA2, 16);
    sA2 += __shfl_xor(sA2, 32);
    iA[n] = 1.0f / sA2;
  }
  const int em0 = (n0 + bx * 4) * DEG + wm * 64;   // abs edge base of this wave
  #pragma unroll
  for (int mt = 0; mt < 4; ++mt)
    #pragma unroll
    for (int i = 0; i < 4; ++i) {
      const int r  = mt * 16 + lg * 4 + i;
      const int d1 = e[MEDGE + em0 + r];
      float* bp = out + (size_t)d1 * 256 + head * 32;
      const float aA = eAv[mt][i] * iA[mt >> 1];
      atomicAdd(bp + lr,      h3[mt][0][i] * aA);
      atomicAdd(bp + 16 + lr, h3[mt][1][i] * aA);
    }
}

// fp32 -> bf16 weight pre-convert
__global__ __launch_bounds__(256) void cvt_w(const float* __restrict__ src,
                                             ushort* __restrict__ dst, int n4)
{
  const int i = blockIdx.x * 256 + threadIdx.x;
  if (i < n4) {
    floatx4 v = *(const floatx4*)(src + (size_t)i * 4);
    short4v r;
    #pragma unroll
    for (int j = 0; j < 4; ++j) r[j] = (short)f2bf(v[j]);
    *(short4v*)(dst + (size_t)i * 4) = r;
  }
}

// ws layout: weights bf16 (2686976 B) | P12 f32 (33554432 B) | chunk buffers
#define WS_WC 0
#define WS_WI (WS_WC + 512*KC)
#define WS_WO (WS_WI + 1536*DD)
#define WB_BYTES   2686976
#define P12_BYTES  33554432
#define CHUNK_OFF  (WB_BYTES + P12_BYTES)

extern "C" void kernel_launch(void* const* d_in, const int* in_sizes, int n_in,
                              void* d_out, int out_size, void* d_ws, size_t ws_size,
                              hipStream_t stream)
{
  (void)in_sizes; (void)n_in;
  const float* x  = (const float*)d_in[0];
  const float* ea = (const float*)d_in[1];
  const int*   e  = (const int*)d_in[2];
  const float* Wc = (const float*)d_in[3];
  const float* bc = (const float*)d_in[4];
  const float* Wi = (const float*)d_in[5];
  const float* bi = (const float*)d_in[6];
  const float* Wo = (const float*)d_in[7];
  const float* bo = (const float*)d_in[8];

  ushort* wsb = (ushort*)d_ws;
  ushort* Wcb = wsb + WS_WC;
  ushort* Wib = wsb + WS_WI;
  ushort* Wob = wsb + WS_WO;
  float*  P12 = (float*)((char*)d_ws + WB_BYTES);

  cvt_w<<<dim3((512 * KC / 4 + 255) / 256), dim3(256), 0, stream>>>(Wc, Wcb, 512 * KC / 4);
  cvt_w<<<dim3((1536 * DD / 4 + 255) / 256), dim3(256), 0, stream>>>(Wi, Wib, 1536 * DD / 4);
  cvt_w<<<dim3((512 * DD / 4 + 255) / 256), dim3(256), 0, stream>>>(Wo, Wob, 512 * DD / 4);

  k0_p12<<<dim3(128, 4), dim3(256), 0, stream>>>(x, Wcb, P12);

  float* out = (float*)d_out;
  hipMemsetAsync(out, 0, (size_t)out_size * sizeof(float), stream);

  // chunk sizing: 5 buffers (ex, Qn, Kn, Vt, AO), each C*32768 bytes
  size_t avail = ws_size > (size_t)CHUNK_OFF ? ws_size - (size_t)CHUNK_OFF : 0;
  long long Cll = (long long)(avail / 163840);
  int C = (int)(Cll > 2048 ? 2048 : Cll);
  C &= ~3;                      // multiple of 4 nodes (128-edge M-tiles)
  if (C < 4) C = 4;
  const size_t seg = (size_t)C * 32768;
  char* cbase = (char*)d_ws + CHUNK_OFF;
  ushort* exC = (ushort*)(cbase);
  ushort* Qn  = (ushort*)(cbase + seg);
  ushort* Kn  = (ushort*)(cbase + 2 * seg);
  ushort* Vt  = (ushort*)(cbase + 3 * seg);
  ushort* AO  = (ushort*)(cbase + 4 * seg);
  const int EC = C * 32;

  for (int n0 = 0; n0 < NNODE; n0 += C) {
    const int cc = (NNODE - n0 < C) ? (NNODE - n0) : C;
    k1_ex  <<<dim3(cc / 2), dim3(256), 0, stream>>>(ea, e, Wcb, bc, P12, exC, n0);
    k2a_qkv<<<dim3(cc / 4, 12), dim3(256), 0, stream>>>(exC, Wib, bi, Qn, Kn, Vt, EC);
    k2b_attn<<<dim3(cc / 2), dim3(512), 0, stream>>>(Qn, Kn, Vt, AO, EC);
    k3_out <<<dim3(cc / 4, 4), dim3(256), 0, stream>>>(AO, e, Wob, bo, out, n0);
  }
}

// Round 10
// 2456.824 us; speedup vs baseline: 3.2179x; 1.0946x over previous
//
#include <hip/hip_runtime.h>
#include <hip/hip_bf16.h>

#define NNODE 8192
#define DEG   32
#define DIN   256
#define EDIM  64
#define KC    576            // 2*DIN + EDIM
#define DD    512            // internal width D
#define MEDGE (NNODE*DEG)
#define EAWP  516            // 512 + 4 f32 pad (k1 LDS)

typedef __attribute__((ext_vector_type(8))) short short8;
typedef __attribute__((ext_vector_type(4))) short short4v;
typedef __attribute__((ext_vector_type(4))) float floatx4;
typedef __attribute__((ext_vector_type(4))) unsigned int uint4v;
typedef unsigned int u32;

__device__ __forceinline__ ushort f2bf(float f) {
  union { float f; unsigned int i; } v; v.f = f;
  return (ushort)((v.i + 0x7fffu + ((v.i >> 16) & 1u)) >> 16);
}
__device__ __forceinline__ u32 pk2(float a, float b) {
  return (u32)f2bf(a) | ((u32)f2bf(b) << 16);
}
__device__ __forceinline__ float gelu_f(float z) {
  return 0.5f * z * (1.0f + erff(z * 0.70710678118654752f));
}
__device__ __forceinline__ floatx4 zero4() { floatx4 v = {0.f, 0.f, 0.f, 0.f}; return v; }

__device__ __forceinline__ short8 ld_cvt8(const float* __restrict__ p) {
  floatx4 a = *(const floatx4*)(p);
  floatx4 b = *(const floatx4*)(p + 4);
  short8 r;
  r[0] = (short)f2bf(a[0]); r[1] = (short)f2bf(a[1]);
  r[2] = (short)f2bf(a[2]); r[3] = (short)f2bf(a[3]);
  r[4] = (short)f2bf(b[0]); r[5] = (short)f2bf(b[1]);
  r[6] = (short)f2bf(b[2]); r[7] = (short)f2bf(b[3]);
  return r;
}

#define MFMA16(a, b, c) __builtin_amdgcn_mfma_f32_16x16x32_bf16((a), (b), (c), 0, 0, 0)

// D-layout -> A/B-frag-layout in-register transform (verified r2-r9).
__device__ __forceinline__ u32 bpsel(int a, u32 v0, u32 v1, bool hi) {
  u32 x0 = (u32)__builtin_amdgcn_ds_bpermute(a, (int)v0);
  u32 x1 = (u32)__builtin_amdgcn_ds_bpermute(a, (int)v1);
  return hi ? x1 : x0;
}
__device__ __forceinline__ short8 frag4(int a0, int a1, bool hi,
                                        u32 t00, u32 t01, u32 t10, u32 t11) {
  uint4v r;
  r[0] = bpsel(a0, t00, t10, hi);
  r[1] = bpsel(a0, t01, t11, hi);
  r[2] = bpsel(a1, t00, t10, hi);
  r[3] = bpsel(a1, t01, t11, hi);
  union { uint4v u; short8 s; } c; c.u = r; return c.s;
}

// async global -> LDS, 16 bytes per lane (wave-uniform LDS base + lane*16)
__device__ __forceinline__ void gl_lds16(const void* g, void* l) {
  __builtin_amdgcn_global_load_lds(
      (const __attribute__((address_space(1))) void*)g,
      (__attribute__((address_space(3))) void*)l,
      16, 0, 0);
}

// stage a [128 rows][64 k] bf16 tile (16 KB) from a matrix with row pitch
// `pitch` (bf16 elems). gbase points at (row0, k0). 256 threads, 4 calls each.
__device__ __forceinline__ void stage_tile(const ushort* gbase, ushort* sdst,
                                           int tid, int pitch) {
  #pragma unroll
  for (int j = 0; j < 4; ++j) {
    const int off = (j * 256 + tid) * 16;   // byte offset in tile
    const int row = off >> 7;               // /128 (row = 128 B)
    const int kb  = off & 127;
    const char* g = (const char*)gbase + (size_t)row * (pitch * 2) + kb;
    char* l = (char*)sdst + j * 4096 + (tid >> 6) * 1024;   // wave-uniform
    gl_lds16(g, l);
  }
}

// ============================================================================
// K0 (tiled): P12 = Xb @ [Wc1^T | Wc2^T] (f32 out). grid (64, 8); 128x128 tile.
// blockIdx.y 0..3 -> P1 (k 0..255), 4..7 -> P2 (k 256..511).
// ============================================================================
__global__ __launch_bounds__(256) void k0_p12(
    const ushort* __restrict__ xb, const ushort* __restrict__ Wcb,
    float* __restrict__ P12)
{
  __shared__ __align__(16) ushort sA[128 * 64];
  __shared__ __align__(16) ushort sB[128 * 64];

  const int bx   = blockIdx.x;
  const int nt8  = blockIdx.y;
  const int koff = (nt8 >= 4) ? 256 : 0;
  const int tid = threadIdx.x;
  const int w = tid >> 6, l = tid & 63, lr = l & 15, lg = l >> 4;
  const int wm = w >> 1, wn = w & 1;

  floatx4 acc[4][4];
  #pragma unroll
  for (int mt = 0; mt < 4; ++mt)
    #pragma unroll
    for (int nt = 0; nt < 4; ++nt) acc[mt][nt] = zero4();

  const ushort* gA = xb + (size_t)bx * 128 * DIN;
  const ushort* gB = Wcb + (size_t)((nt8 & 3) * 128) * KC + koff;

  for (int ks = 0; ks < 4; ++ks) {
    stage_tile(gA + ks * 64, sA, tid, DIN);
    stage_tile(gB + ks * 64, sB, tid, KC);
    __syncthreads();
    #pragma unroll
    for (int ksub = 0; ksub < 2; ++ksub) {
      short8 a[4], b[4];
      #pragma unroll
      for (int mt = 0; mt < 4; ++mt)
        a[mt] = *(const short8*)(&sA[(wm * 64 + mt * 16 + lr) * 64 + ksub * 32 + lg * 8]);
      #pragma unroll
      for (int nt = 0; nt < 4; ++nt)
        b[nt] = *(const short8*)(&sB[(wn * 64 + nt * 16 + lr) * 64 + ksub * 32 + lg * 8]);
      #pragma unroll
      for (int mt = 0; mt < 4; ++mt)
        #pragma unroll
        for (int nt = 0; nt < 4; ++nt)
          acc[mt][nt] = MFMA16(a[mt], b[nt], acc[mt][nt]);
    }
    __syncthreads();
  }
  const int c0 = nt8 * 128 + wn * 64;
  const int r0 = bx * 128 + wm * 64;
  #pragma unroll
  for (int mt = 0; mt < 4; ++mt)
    #pragma unroll
    for (int nt = 0; nt < 4; ++nt)
      #pragma unroll
      for (int i = 0; i < 4; ++i)
        P12[(size_t)(r0 + mt * 16 + lg * 4 + i) * 1024 + c0 + nt * 16 + lr] = acc[mt][nt][i];
}

// ============================================================================
// K1 (REWRITE): ex = gelu(gelu(P1[src] + P2[dst] + ea@Wc3^T + bc)).
// Per block: 2 nodes, processed one node (32 edges) at a time.
// Phase A: EAW via MFMA -> f32 LDS; stage P1[src]+bc -> LDS.
// Phase B: 8 threads/edge, float4 P2 gather (256 B contiguous per edge).
// ============================================================================
__global__ __launch_bounds__(256, 2) void k1_ex(
    const float* __restrict__ ea, const int* __restrict__ e,
    const ushort* __restrict__ Wcb, const float* __restrict__ bc,
    const float* __restrict__ P12,
    ushort* __restrict__ exC, int n0)
{
  __shared__ float sEAW[32 * EAWP];   // [32 edges][512] f32, pad 4
  __shared__ float sP1B[512];         // P1[src] + bc

  const int m0  = (n0 + blockIdx.x * 2) * DEG;
  const int le0 = blockIdx.x * 64;
  const int tid = threadIdx.x;
  const int w = tid >> 6, l = tid & 63, lr = l & 15, lg = l >> 4;

  for (int nn = 0; nn < 2; ++nn) {
    // stage P1[src]+bc (first 128 threads, float4)
    if (tid < 128) {
      const int node = e[m0 + nn * DEG];
      floatx4 a = *(const floatx4*)(P12 + (size_t)node * 1024 + tid * 4);
      floatx4 b = *(const floatx4*)(bc + tid * 4);
      #pragma unroll
      for (int q = 0; q < 4; ++q) a[q] += b[q];
      *(floatx4*)(&sP1B[tid * 4]) = a;
    }
    // phase A: EAW = ea @ Wc3^T for this node's 32 edges -> sEAW (f32)
    for (int p = 0; p < 2; ++p) {
      const int cb = w * 128 + p * 64;
      floatx4 acc[2][4];
      #pragma unroll
      for (int et = 0; et < 2; ++et)
        #pragma unroll
        for (int nt = 0; nt < 4; ++nt) acc[et][nt] = zero4();
      #pragma unroll
      for (int s = 0; s < 2; ++s) {
        short8 bfr[4];
        #pragma unroll
        for (int nt = 0; nt < 4; ++nt)
          bfr[nt] = *(const short8*)(Wcb + (size_t)(cb + nt * 16 + lr) * KC + 512 + s * 32 + lg * 8);
        #pragma unroll
        for (int et = 0; et < 2; ++et) {
          short8 af = ld_cvt8(ea + (size_t)(m0 + nn * 32 + et * 16 + lr) * EDIM + s * 32 + lg * 8);
          #pragma unroll
          for (int nt = 0; nt < 4; ++nt)
            acc[et][nt] = MFMA16(af, bfr[nt], acc[et][nt]);
        }
      }
      #pragma unroll
      for (int et = 0; et < 2; ++et)
        #pragma unroll
        for (int nt = 0; nt < 4; ++nt)
          #pragma unroll
          for (int i = 0; i < 4; ++i)
            sEAW[(et * 16 + lg * 4 + i) * EAWP + cb + nt * 16 + lr] = acc[et][nt][i];
    }
    __syncthreads();

    // phase B: 8 threads per edge; 8 floats per iteration
    {
      const int eloc = tid >> 3;     // 0..31
      const int k8   = tid & 7;
      const int em   = m0 + nn * 32 + eloc;
      const int dn   = e[MEDGE + em];
      const float* p2r = P12 + (size_t)dn * 1024 + 512;
      const float* erow = &sEAW[eloc * EAWP];
      ushort* exrow = exC + (size_t)(le0 + nn * 32 + eloc) * DD;
      #pragma unroll
      for (int j = 0; j < 8; ++j) {
        const int col = j * 64 + k8 * 8;
        floatx4 q0 = *(const floatx4*)(p2r + col);
        floatx4 q1 = *(const floatx4*)(p2r + col + 4);
        floatx4 e0 = *(const floatx4*)(erow + col);
        floatx4 e1 = *(const floatx4*)(erow + col + 4);
        floatx4 b0 = *(const floatx4*)(&sP1B[col]);
        floatx4 b1 = *(const floatx4*)(&sP1B[col + 4]);
        short8 r;
        #pragma unroll
        for (int q = 0; q < 4; ++q) {
          r[q]     = (short)f2bf(gelu_f(gelu_f(e0[q] + b0[q] + q0[q])));
          r[4 + q] = (short)f2bf(gelu_f(gelu_f(e1[q] + b1[q] + q1[q])));
        }
        *(short8*)(exrow + col) = r;
      }
    }
    __syncthreads();
  }
}

// ============================================================================
// K2a (r9 verbatim, pitch arg): QKV = exC @ Wi^T. grid (EC/128, 12).
// ============================================================================
__global__ __launch_bounds__(256) void k2a_qkv(
    const ushort* __restrict__ exC, const ushort* __restrict__ Wib,
    const float* __restrict__ bi,
    ushort* __restrict__ Qn, ushort* __restrict__ Kn, ushort* __restrict__ Vt,
    int EC)
{
  __shared__ __align__(16) ushort sA[128 * 64];
  __shared__ __align__(16) ushort sB[128 * 64];

  const int bx   = blockIdx.x;
  const int nt12 = blockIdx.y;
  const int tid = threadIdx.x;
  const int w = tid >> 6, l = tid & 63, lr = l & 15, lg = l >> 4;
  const int wm = w >> 1, wn = w & 1;

  floatx4 acc[4][4];
  #pragma unroll
  for (int mt = 0; mt < 4; ++mt)
    #pragma unroll
    for (int nt = 0; nt < 4; ++nt) acc[mt][nt] = zero4();

  const ushort* gA = exC + (size_t)bx * 128 * DD;
  const ushort* gB = Wib + (size_t)nt12 * 128 * DD;

  for (int ks = 0; ks < 8; ++ks) {
    stage_tile(gA + ks * 64, sA, tid, DD);
    stage_tile(gB + ks * 64, sB, tid, DD);
    __syncthreads();
    #pragma unroll
    for (int ksub = 0; ksub < 2; ++ksub) {
      short8 a[4], b[4];
      #pragma unroll
      for (int mt = 0; mt < 4; ++mt)
        a[mt] = *(const short8*)(&sA[(wm * 64 + mt * 16 + lr) * 64 + ksub * 32 + lg * 8]);
      #pragma unroll
      for (int nt = 0; nt < 4; ++nt)
        b[nt] = *(const short8*)(&sB[(wn * 64 + nt * 16 + lr) * 64 + ksub * 32 + lg * 8]);
      #pragma unroll
      for (int mt = 0; mt < 4; ++mt)
        #pragma unroll
        for (int nt = 0; nt < 4; ++nt)
          acc[mt][nt] = MFMA16(a[mt], b[nt], acc[mt][nt]);
    }
    __syncthreads();
  }

  const int o0    = nt12 * 128 + wn * 64;
  const int seg   = o0 >> 9;
  const int h     = (o0 >> 6) & 7;
  const int ebase = bx * 128 + wm * 64;

  if (seg < 2) {
    ushort* Dst = (seg == 0 ? Qn : Kn) + (size_t)h * EC * 64;
    #pragma unroll
    for (int nt = 0; nt < 4; ++nt) {
      const int ch = nt * 16 + lr;
      const float bias = bi[o0 + ch];
      #pragma unroll
      for (int mt = 0; mt < 4; ++mt)
        #pragma unroll
        for (int i = 0; i < 4; ++i)
          Dst[(size_t)(ebase + mt * 16 + lg * 4 + i) * 64 + ch] = f2bf(acc[mt][nt][i] + bias);
    }
  } else {
    ushort* Dv = Vt + (size_t)h * 64 * EC;
    #pragma unroll
    for (int nt = 0; nt < 4; ++nt) {
      const int ch = nt * 16 + lr;
      const float bias = bi[o0 + ch];
      #pragma unroll
      for (int mt = 0; mt < 4; ++mt) {
        short4v pk;
        #pragma unroll
        for (int i = 0; i < 4; ++i) pk[i] = (short)f2bf(acc[mt][nt][i] + bias);
        *(short4v*)(&Dv[(size_t)ch * EC + ebase + mt * 16 + lg * 4]) = pk;
      }
    }
  }
}

// ============================================================================
// K2b: attention (r9 verbatim). 512 thr / 8 waves, wave = head; 2 nodes/block.
// ============================================================================
__global__ __launch_bounds__(512, 3) void k2b_attn(
    const ushort* __restrict__ Qn, const ushort* __restrict__ Kn,
    const ushort* __restrict__ Vt,
    ushort* __restrict__ aoC, int EC)
{
  const int le0 = blockIdx.x * 64;
  const int tid = threadIdx.x;
  const int w = tid >> 6, l = tid & 63, lr = l & 15, lg = l >> 4;

  const ushort* Qh = Qn + (size_t)w * EC * 64;
  const ushort* Kh = Kn + (size_t)w * EC * 64;
  const ushort* Vh = Vt + (size_t)w * 64 * EC;

  const int pa0 = ((2 * (lg & 1)) * 16 + lr) * 4;
  const int pa1 = pa0 + 64;
  const bool hi = ((lg >> 1) & 1) != 0;

  #pragma unroll
  for (int n = 0; n < 2; ++n) {
    const int e0 = le0 + n * 32;

    floatx4 sacc[2][2];
    #pragma unroll
    for (int a = 0; a < 2; ++a)
      #pragma unroll
      for (int b = 0; b < 2; ++b) sacc[a][b] = zero4();
    #pragma unroll
    for (int ks2 = 0; ks2 < 2; ++ks2) {
      short8 kfr[2], qfr[2];
      #pragma unroll
      for (int mt = 0; mt < 2; ++mt)
        kfr[mt] = *(const short8*)(Kh + (size_t)(e0 + mt * 16 + lr) * 64 + ks2 * 32 + lg * 8);
      #pragma unroll
      for (int nt = 0; nt < 2; ++nt)
        qfr[nt] = *(const short8*)(Qh + (size_t)(e0 + nt * 16 + lr) * 64 + ks2 * 32 + lg * 8);
      #pragma unroll
      for (int mt = 0; mt < 2; ++mt)
        #pragma unroll
        for (int nt = 0; nt < 2; ++nt)
          sacc[mt][nt] = MFMA16(kfr[mt], qfr[nt], sacc[mt][nt]);
    }

    u32 ppk[2][4];
    #pragma unroll
    for (int nt = 0; nt < 2; ++nt) {
      float s[2][4];
      float mx = -1e30f;
      #pragma unroll
      for (int mt = 0; mt < 2; ++mt)
        #pragma unroll
        for (int i = 0; i < 4; ++i) {
          s[mt][i] = sacc[mt][nt][i] * 0.125f;
          mx = fmaxf(mx, s[mt][i]);
        }
      mx = fmaxf(mx, __shfl_xor(mx, 16));
      mx = fmaxf(mx, __shfl_xor(mx, 32));
      float sm = 0.f;
      #pragma unroll
      for (int mt = 0; mt < 2; ++mt)
        #pragma unroll
        for (int i = 0; i < 4; ++i) { s[mt][i] = expf(s[mt][i] - mx); sm += s[mt][i]; }
      sm += __shfl_xor(sm, 16);
      sm += __shfl_xor(sm, 32);
      const float inv = 1.0f / sm;
      #pragma unroll
      for (int mt = 0; mt < 2; ++mt) {
        ppk[mt][2 * nt + 0] = pk2(s[mt][0] * inv, s[mt][1] * inv);
        ppk[mt][2 * nt + 1] = pk2(s[mt][2] * inv, s[mt][3] * inv);
      }
    }

    short8 paf[2], vbf[4];
    #pragma unroll
    for (int qt = 0; qt < 2; ++qt)
      paf[qt] = frag4(pa0, pa1, hi, ppk[0][2 * qt + 0], ppk[0][2 * qt + 1],
                                    ppk[1][2 * qt + 0], ppk[1][2 * qt + 1]);
    #pragma unroll
    for (int nt = 0; nt < 4; ++nt)
      vbf[nt] = *(const short8*)(Vh + (size_t)(nt * 16 + lr) * EC + e0 + lg * 8);
    #pragma unroll
    for (int qt = 0; qt < 2; ++qt)
      #pragma unroll
      for (int nt = 0; nt < 4; ++nt) {
        floatx4 o = MFMA16(paf[qt], vbf[nt], zero4());
        #pragma unroll
        for (int i = 0; i < 4; ++i)
          aoC[(size_t)(e0 + qt * 16 + lg * 4 + i) * DD + w * 64 + nt * 16 + lr] = f2bf(o[i]);
      }
  }
}

// ============================================================================
// K3 (r9 verbatim): h = gelu(AO @ Wo^T + bo), weighted-mean agg, atomic scatter.
// ============================================================================
__global__ __launch_bounds__(256) void k3_out(
    const ushort* __restrict__ aoC, const int* __restrict__ e,
    const ushort* __restrict__ Wob, const float* __restrict__ bo,
    float* __restrict__ out, int n0)
{
  __shared__ __align__(16) ushort sA[128 * 64];
  __shared__ __align__(16) ushort sB[128 * 64];

  const int bx  = blockIdx.x;
  const int nt4 = blockIdx.y;
  const int tid = threadIdx.x;
  const int w = tid >> 6, l = tid & 63, lr = l & 15, lg = l >> 4;
  const int wm = w >> 1, wn = w & 1;

  floatx4 acc[4][4];
  #pragma unroll
  for (int mt = 0; mt < 4; ++mt)
    #pragma unroll
    for (int nt = 0; nt < 4; ++nt) acc[mt][nt] = zero4();

  const ushort* gA = aoC + (size_t)bx * 128 * DD;
  const ushort* gB = Wob + (size_t)nt4 * 128 * DD;

  for (int ks = 0; ks < 8; ++ks) {
    stage_tile(gA + ks * 64, sA, tid, DD);
    stage_tile(gB + ks * 64, sB, tid, DD);
    __syncthreads();
    #pragma unroll
    for (int ksub = 0; ksub < 2; ++ksub) {
      short8 a[4], b[4];
      #pragma unroll
      for (int mt = 0; mt < 4; ++mt)
        a[mt] = *(const short8*)(&sA[(wm * 64 + mt * 16 + lr) * 64 + ksub * 32 + lg * 8]);
      #pragma unroll
      for (int nt = 0; nt < 4; ++nt)
        b[nt] = *(const short8*)(&sB[(wn * 64 + nt * 16 + lr) * 64 + ksub * 32 + lg * 8]);
      #pragma unroll
      for (int mt = 0; mt < 4; ++mt)
        #pragma unroll
        for (int nt = 0; nt < 4; ++nt)
          acc[mt][nt] = MFMA16(a[mt], b[nt], acc[mt][nt]);
    }
    __syncthreads();
  }

  const int head = nt4 * 2 + wn;
  floatx4 h3[4][4];
  #pragma unroll
  for (int nt = 0; nt < 4; ++nt) {
    const float bias = bo[nt4 * 128 + wn * 64 + nt * 16 + lr];
    #pragma unroll
    for (int mt = 0; mt < 4; ++mt)
      #pragma unroll
      for (int i = 0; i < 4; ++i)
        h3[mt][nt][i] = gelu_f(acc[mt][nt][i] + bias);
  }
  float lgA[4][4];
  #pragma unroll
  for (int mt = 0; mt < 4; ++mt)
    #pragma unroll
    for (int i = 0; i < 4; ++i) {
      float tA = h3[mt][2][i] + h3[mt][3][i];
      #pragma unroll
      for (int d2 = 1; d2 < 16; d2 <<= 1) tA += __shfl_xor(tA, d2);
      lgA[mt][i] = tA * (1.0f / 32.0f);
    }
  float eAv[4][4], iA[2];
  #pragma unroll
  for (int n = 0; n < 2; ++n) {
    float mx = -1e30f;
    #pragma unroll
    for (int m2 = 0; m2 < 2; ++m2)
      #pragma unroll
      for (int i = 0; i < 4; ++i) mx = fmaxf(mx, lgA[2 * n + m2][i]);
    mx = fmaxf(mx, __shfl_xor(mx, 16));
    mx = fmaxf(mx, __shfl_xor(mx, 32));
    float sA2 = 0.f;
    #pragma unroll
    for (int m2 = 0; m2 < 2; ++m2)
      #pragma unroll
      for (int i = 0; i < 4; ++i) {
        eAv[2 * n + m2][i] = expf(lgA[2 * n + m2][i] - mx);
        sA2 += eAv[2 * n + m2][i];
      }
    sA2 += __shfl_xor(sA2, 16);
    sA2 += __shfl_xor(sA2, 32);
    iA[n] = 1.0f / sA2;
  }
  const int em0 = (n0 + bx * 4) * DEG + wm * 64;
  #pragma unroll
  for (int mt = 0; mt < 4; ++mt)
    #pragma unroll
    for (int i = 0; i < 4; ++i) {
      const int r  = mt * 16 + lg * 4 + i;
      const int d1 = e[MEDGE + em0 + r];
      float* bp = out + (size_t)d1 * 256 + head * 32;
      const float aA = eAv[mt][i] * iA[mt >> 1];
      atomicAdd(bp + lr,      h3[mt][0][i] * aA);
      atomicAdd(bp + 16 + lr, h3[mt][1][i] * aA);
    }
}

// fp32 -> bf16 pre-convert
__global__ __launch_bounds__(256) void cvt_w(const float* __restrict__ src,
                                             ushort* __restrict__ dst, int n4)
{
  const int i = blockIdx.x * 256 + threadIdx.x;
  if (i < n4) {
    floatx4 v = *(const floatx4*)(src + (size_t)i * 4);
    short4v r;
    #pragma unroll
    for (int j = 0; j < 4; ++j) r[j] = (short)f2bf(v[j]);
    *(short4v*)(dst + (size_t)i * 4) = r;
  }
}

// ws layout: weights bf16 | xb bf16 (4 MB) | P12 f32 (33.5 MB) | chunk buffers
#define WS_WC 0
#define WS_WI (WS_WC + 512*KC)
#define WS_WO (WS_WI + 1536*DD)
#define WB_BYTES   2686976
#define XB_BYTES   4194304
#define P12_BYTES  33554432
#define CHUNK_OFF  (WB_BYTES + XB_BYTES + P12_BYTES)

extern "C" void kernel_launch(void* const* d_in, const int* in_sizes, int n_in,
                              void* d_out, int out_size, void* d_ws, size_t ws_size,
                              hipStream_t stream)
{
  (void)in_sizes; (void)n_in;
  const float* x  = (const float*)d_in[0];
  const float* ea = (const float*)d_in[1];
  const int*   e  = (const int*)d_in[2];
  const float* Wc = (const float*)d_in[3];
  const float* bc = (const float*)d_in[4];
  const float* Wi = (const float*)d_in[5];
  const float* bi = (const float*)d_in[6];
  const float* Wo = (const float*)d_in[7];
  const float* bo = (const float*)d_in[8];

  ushort* wsb = (ushort*)d_ws;
  ushort* Wcb = wsb + WS_WC;
  ushort* Wib = wsb + WS_WI;
  ushort* Wob = wsb + WS_WO;
  ushort* xb  = (ushort*)((char*)d_ws + WB_BYTES);
  float*  P12 = (float*)((char*)d_ws + WB_BYTES + XB_BYTES);

  cvt_w<<<dim3((512 * KC / 4 + 255) / 256), dim3(256), 0, stream>>>(Wc, Wcb, 512 * KC / 4);
  cvt_w<<<dim3((1536 * DD / 4 + 255) / 256), dim3(256), 0, stream>>>(Wi, Wib, 1536 * DD / 4);
  cvt_w<<<dim3((512 * DD / 4 + 255) / 256), dim3(256), 0, stream>>>(Wo, Wob, 512 * DD / 4);
  cvt_w<<<dim3((NNODE * DIN / 4 + 255) / 256), dim3(256), 0, stream>>>(x, xb, NNODE * DIN / 4);

  k0_p12<<<dim3(64, 8), dim3(256), 0, stream>>>(xb, Wcb, P12);

  float* out = (float*)d_out;
  hipMemsetAsync(out, 0, (size_t)out_size * sizeof(float), stream);

  // chunk sizing: 5 buffers (ex, Qn, Kn, Vt, AO), each C*32768 bytes
  size_t avail = ws_size > (size_t)CHUNK_OFF ? ws_size - (size_t)CHUNK_OFF : 0;
  long long Cll = (long long)(avail / 163840);
  int C = (int)(Cll > 2048 ? 2048 : Cll);
  C &= ~3;                      // multiple of 4 nodes (128-edge M-tiles)
  if (C < 4) C = 4;
  const size_t seg = (size_t)C * 32768;
  char* cbase = (char*)d_ws + CHUNK_OFF;
  ushort* exC = (ushort*)(cbase);
  ushort* Qn  = (ushort*)(cbase + seg);
  ushort* Kn  = (ushort*)(cbase + 2 * seg);
  ushort* Vt  = (ushort*)(cbase + 3 * seg);
  ushort* AO  = (ushort*)(cbase + 4 * seg);
  const int EC = C * 32;

  for (int n0 = 0; n0 < NNODE; n0 += C) {
    const int cc = (NNODE - n0 < C) ? (NNODE - n0) : C;
    k1_ex  <<<dim3(cc / 2), dim3(256), 0, stream>>>(ea, e, Wcb, bc, P12, exC, n0);
    k2a_qkv<<<dim3(cc / 4, 12), dim3(256), 0, stream>>>(exC, Wib, bi, Qn, Kn, Vt, EC);
    k2b_attn<<<dim3(cc / 2), dim3(512), 0, stream>>>(Qn, Kn, Vt, AO, EC);
    k3_out <<<dim3(cc / 4, 4), dim3(256), 0, stream>>>(AO, e, Wob, bo, out, n0);
  }
}